// Round 1
// baseline (207.422 us; speedup 1.0000x reference)
//
#include <hip/hip_runtime.h>
#include <hip/hip_bf16.h>
#include <math.h>

#define N     12
#define HID   64
#define STP   68     // padded row stride for bufL/bufR (272 B rows, 16B-aligned)
#define SLOPE 0.2f
#define ALPHA 0.1f

typedef float v2f __attribute__((ext_vector_type(2)));
typedef float v4f __attribute__((ext_vector_type(4)));
typedef int   i4  __attribute__((ext_vector_type(4)));
typedef short v8s __attribute__((ext_vector_type(8)));

static __device__ __forceinline__ v8s as_v8s(i4 v) {
    union { i4 a; v8s b; } u; u.a = v; return u.b;
}

// flat output offsets (float32 elements)
#define OUT0 0          // batch[:,:,:4]
#define OUT1 196608     // batch[:,:,4:5]
#define OUT2 245760     // logits
#define OUT3 442368     // values
#define OUT4 491520     // latent

// ws layout identical to previous round (prep_kernel unchanged):
//   [0,4096)       enc_w2 transposed fp32
//   [4096,16384)   6 GAT matrices bf16 B-fragments
//   [16384,16640)  labT fp32
__global__ void prep_kernel(const float* __restrict__ enc_w2,
                            const float* __restrict__ g2_wl, const float* __restrict__ g2_wr,
                            const float* __restrict__ g3_wl, const float* __restrict__ g3_wr,
                            const float* __restrict__ g4_wl, const float* __restrict__ g4_wr,
                            const float* __restrict__ lab_w,
                            float* __restrict__ ws) {
    int t = threadIdx.x;
    int bx = blockIdx.x;
    if (bx < 64) {                       // enc_w2 fp32 transpose
        int c = bx;
        ws[t*64 + c] = enc_w2[c*64 + t];
        return;
    }
    if (bx == 112) {                     // labT
        #pragma unroll
        for (int c = 0; c < 4; c++) ws[16384 + c*64 + t] = lab_w[t*4 + c];
        return;
    }
    int idx = bx - 64;
    int mat = idx >> 3, rem = idx & 7;
    int kt = rem >> 2, nt = rem & 3;
    const float* src;
    switch (mat) {
        case 0: src = g2_wl; break;
        case 1: src = g2_wr; break;
        case 2: src = g3_wl; break;
        case 3: src = g3_wr; break;
        case 4: src = g4_wl; break;
        default: src = g4_wr; break;
    }
    int quad = t >> 4, col = t & 15;
    int n = nt*16 + col;
    unsigned* dst = (unsigned*)(ws + 4096) + mat*2048 + (kt*4+nt)*256 + t*4;
    #pragma unroll
    for (int jp = 0; jp < 4; jp++) {
        int k0 = kt*32 + quad*8 + 2*jp;
        __hip_bfloat16 h0 = __float2bfloat16(src[(k0+0)*64 + n]);
        __hip_bfloat16 h1 = __float2bfloat16(src[(k0+1)*64 + n]);
        unsigned u0 = *(unsigned short*)&h0, u1 = *(unsigned short*)&h1;
        dst[jp] = u0 | (u1 << 16);
    }
}

// R10: TWO waves per graph (128-thread blocks). 4096 blocks x 2 waves = 32 waves/CU
// (was 16 = 50% cap). Row-parallel sections split 6 rows/wave; loop-length-bound
// sections (score/softmax/latent/heads) split their inner loop across lane pairs
// so per-graph instruction count stays ~constant while waves/SIMD doubles 4->8.
// LDS: bufL(816)+bufR(816)+xB(768)+pool(144) = 2544 floats = 10176 B -> 16 blk/CU.
template<bool TW>
__global__ __launch_bounds__(128, 8) void gae_kernel(
    const float* __restrict__ batch,
    const float* __restrict__ enc_w1, const float* __restrict__ enc_b1,
    const float* __restrict__ enc_w2, const float* __restrict__ enc_b2,
    const float* __restrict__ enc_w3, const float* __restrict__ enc_b3,
    const float* __restrict__ g1_wl, const float* __restrict__ g1_wr,
    const float* __restrict__ g1_att, const float* __restrict__ g1_b,
    const float* __restrict__ g2_wl, const float* __restrict__ g2_wr,
    const float* __restrict__ g2_att, const float* __restrict__ g2_b,
    const float* __restrict__ g3_wl, const float* __restrict__ g3_wr,
    const float* __restrict__ g3_att, const float* __restrict__ g3_b,
    const float* __restrict__ g4_wl, const float* __restrict__ g4_wr,
    const float* __restrict__ g4_att, const float* __restrict__ g4_b,
    const float* __restrict__ lab_w, const float* __restrict__ lab_b,
    const float* __restrict__ val_w, const float* __restrict__ val_b,
    const float* __restrict__ skip_w, const float* __restrict__ skip_b,
    const float* __restrict__ wsT,
    float* __restrict__ out)
{
    const int b = blockIdx.x;
    const int t = threadIdx.x;
    const int w = t >> 6;       // wave id (0/1) -- uniform per wave
    const int l = t & 63;       // lane
    const int r0 = w * 6;       // first row owned by this wave

    __shared__ __align__(16) float lds[2544];
    float* bufL  = lds;                          // stride STP, rows 0..11
    float* bufR  = lds + N*STP;                  // stride STP
    float* xB    = lds + 2*N*STP;                // stride HID (x1/x2 storage)
    float* pool  = lds + 2*N*STP + N*HID;        // 144 floats: batch/e-matrix
    float* coord = pool + 108;                   // 36 floats latent coords
    // transient scratch inside pool (dead once e-scores are written):
    //   pool[64..70)  gabriel ballot masks (6 dwords)
    //   pool[72..104) compacted pair lists (64 B per wave)

    const v2f z2 = {0.f, 0.f};
    const v4f z4 = {0.f, 0.f, 0.f, 0.f};
    const v4f s4 = {SLOPE, SLOPE, SLOPE, SLOPE};

    // ---- stage batch (own half) + passthrough outputs 0/1; no barrier needed:
    // each wave stages exactly the rows its own encoder reads ----
    if (l < 30) {
        int idx = w*30 + l;
        float v = batch[b*(N*5) + idx];
        pool[idx] = v;
        int i = idx / 5, f = idx - (idx/5)*5;
        if (f < 4) out[OUT0 + (size_t)b*(N*4) + i*4 + f] = v;
        else       out[OUT1 + (size_t)b*N + i] = v;
    }

    // ---- encoder layer 1 (own 6 rows) ----
    {
        float acc[6];
        float bias = enc_b1[l];
        #pragma unroll
        for (int i=0;i<6;i++) acc[i] = bias;
        #pragma unroll
        for (int f=0; f<5; f++) {
            float wv = enc_w1[f*HID + l];
            #pragma unroll
            for (int i=0;i<6;i++) acc[i] = fmaf(pool[(r0+i)*5+f], wv, acc[i]);
        }
        #pragma unroll
        for (int i=0;i<6;i++) bufL[(r0+i)*STP + l] = fmaxf(acc[i], 0.f);
    }

    // ---- encoder layer 2 (own 6 rows; fp32, K-loop ROLLED) ----
    {
        v2f acc[6];
        #pragma unroll
        for (int i=0;i<6;i++) acc[i] = z2;
        const float* w2p = TW ? (wsT + l*HID) : nullptr;
        for (int c=0;c<HID;c+=4) {
            v2f w01, w23;
            if (TW) {
                v4f w4 = *reinterpret_cast<const v4f*>(&w2p[c]);
                w01 = w4.xy; w23 = w4.zw;
            } else {
                w01 = (v2f){enc_w2[(c+0)*HID+l], enc_w2[(c+1)*HID+l]};
                w23 = (v2f){enc_w2[(c+2)*HID+l], enc_w2[(c+3)*HID+l]};
            }
            #pragma unroll
            for (int i=0;i<6;i++) {
                v4f xv = *reinterpret_cast<const v4f*>(&bufL[(r0+i)*STP + c]);
                acc[i] = __builtin_elementwise_fma(xv.xy, w01, acc[i]);
                acc[i] = __builtin_elementwise_fma(xv.zw, w23, acc[i]);
            }
        }
        float bias = enc_b2[l];
        #pragma unroll
        for (int i=0;i<6;i++) bufR[(r0+i)*STP + l] = fmaxf(bias + acc[i].x + acc[i].y, 0.f);
    }

    // ---- latent (own rows; k-dim split across lane pairs) ----
    if (l < 36) {
        int i   = r0 + l/6;
        int rem = l - (l/6)*6;
        int c   = rem >> 1, sb = rem & 1;
        float acc = 0.f;
        for (int k = sb*32; k < sb*32 + 32; k += 4) {
            v4f xv = *reinterpret_cast<const v4f*>(&bufR[i*STP + k]);
            acc = fmaf(xv.x, enc_w3[(k+0)*3+c], acc);
            acc = fmaf(xv.y, enc_w3[(k+1)*3+c], acc);
            acc = fmaf(xv.z, enc_w3[(k+2)*3+c], acc);
            acc = fmaf(xv.w, enc_w3[(k+3)*3+c], acc);
        }
        acc += __shfl_xor(acc, 1);
        if (sb == 0) {
            acc += enc_b3[c];
            coord[i*3 + c] = acc;
            out[OUT4 + (size_t)b*(N*3) + i*3 + c] = acc;
        }
    }

    // ---- skip connection (own rows, own-wave coords) -> registers ----
    float skipv[6];
    {
        float w0 = skip_w[l], w1 = skip_w[HID+l], w2v = skip_w[2*HID+l];
        float bias = skip_b[l];
        #pragma unroll
        for (int i=0;i<6;i++) {
            float v = bias;
            v = fmaf(coord[(r0+i)*3+0], w0, v);
            v = fmaf(coord[(r0+i)*3+1], w1, v);
            v = fmaf(coord[(r0+i)*3+2], w2v, v);
            skipv[i] = v;
        }
    }
    __syncthreads();   // B0: all coords visible

    // ---- Gabriel adjacency (wave0: pairs 0-63; wave1: 64-127 + 128-143) ----
    auto gab = [&](int i, int j)->bool {
        if (i == j) return false;
        float pix = coord[i*3], piy = coord[i*3+1];
        float pjx = coord[j*3], pjy = coord[j*3+1];
        float mx = (pix + pjx) * 0.5f, my = (piy + pjy) * 0.5f;
        float dx = pix - pjx, dy = piy - pjy;
        float r2 = (dx*dx + dy*dy) * 0.25f;
        bool g = true;
        #pragma unroll
        for (int k=0;k<N;k++) {
            float ex = coord[k*3] - mx, ey = coord[k*3+1] - my;
            bool ok = (k == i) || (k == j) || (ex*ex + ey*ey > r2);
            g = g && ok;
        }
        return g;
    };
    unsigned* pu = (unsigned*)(pool + 64);
    if (w == 0) {
        int i0 = (l*171) >> 11, j0 = l - i0*N;
        unsigned long long m0 = __ballot(gab(i0, j0));
        if (l == 0) { pu[0] = (unsigned)m0; pu[1] = (unsigned)(m0 >> 32); }
    } else {
        int p1 = 64 + l;
        int i1 = (p1*171) >> 11, j1 = p1 - i1*N;
        unsigned long long m1 = __ballot(gab(i1, j1));
        int p2 = (l < 16) ? (128 + l) : 143;
        int i2 = (p2*171) >> 11, j2 = p2 - i2*N;
        unsigned long long m2 = __ballot((l < 16) && gab(i2, j2));
        if (l == 0) { pu[2] = (unsigned)m1; pu[3] = (unsigned)(m1 >> 32);
                      pu[4] = (unsigned)m2; pu[5] = (unsigned)(m2 >> 32); }
    }
    __syncthreads();   // B0b: masks visible

    const unsigned long long gb0 = (unsigned long long)pu[0] | ((unsigned long long)pu[1] << 32);
    const unsigned long long gb1 = (unsigned long long)pu[2] | ((unsigned long long)pu[3] << 32);
    const unsigned long long gb2 = (unsigned long long)pu[4] | ((unsigned long long)pu[5] << 32);
    auto gbit = [&](int p)->int {
        unsigned long long m = (p < 64) ? gb0 : ((p < 128) ? gb1 : gb2);
        return (int)((m >> (p & 63)) & 1ull);
    };
    auto mbcnt64 = [&](unsigned long long m)->int {
        return __builtin_amdgcn_mbcnt_hi((unsigned)(m >> 32),
               __builtin_amdgcn_mbcnt_lo((unsigned)m, 0));
    };

    // ---- per-row adjacency mask for softmax (2 lanes per row) ----
    unsigned rowm = 0;
    if (l < 12) {
        int ri = r0 + (l >> 1);
        #pragma unroll
        for (int j=0;j<N;j++)
            rowm |= (unsigned)(gbit(ri*N + j) | gbit(j*N + ri) | (ri == j)) << j;
    }

    // ---- compact valid pairs (per-wave list, per-wave slots) ----
    int nW = 0;
    bool ovC = false; int im2 = 0, jm2 = 0, myp2 = 0;
    unsigned char* mylist = (unsigned char*)(pool + 72) + w*64;
    if (w == 0) {
        int i0 = (l*171) >> 11, j0 = l - i0*N;
        int a = gbit(l) | gbit(j0*N + i0) | (i0 == j0);
        unsigned long long am = __ballot(a != 0);
        if (a) mylist[mbcnt64(am)] = (unsigned char)l;
        nW = __popcll(am);                         // <= 64, never overflows
    } else {
        int p1 = 64 + l;
        int i1 = (p1*171) >> 11, j1 = p1 - i1*N;
        int aB = gbit(p1) | gbit(j1*N + i1) | (i1 == j1);
        int p2 = (l < 16) ? (128 + l) : 143;
        int i2 = (p2*171) >> 11, j2 = p2 - i2*N;
        int aC = (l < 16) ? (gbit(p2) | gbit(j2*N + i2) | (i2 == j2)) : 0;
        unsigned long long am1 = __ballot(aB != 0);
        unsigned long long am2 = __ballot(aC != 0);
        int c1 = __popcll(am1);
        int idx1 = mbcnt64(am1);
        int idx2 = c1 + mbcnt64(am2);
        if (aB) mylist[idx1] = (unsigned char)p1;
        if (aC && idx2 < 64) mylist[idx2] = (unsigned char)p2;
        ovC = aC && (idx2 >= 64);                  // rare (planarity: total <= ~68)
        im2 = i2; jm2 = j2; myp2 = p2;
        int n = c1 + __popcll(am2);
        nW = n < 64 ? n : 64;
    }
    // score assignment: 2 lanes per pair (h-dim split), up to 2 passes of 32 pairs
    const int pidm = l & 31, sub = l >> 5;
    const bool actA = pidm < nW;
    const bool actB = (32 + pidm) < nW;
    const bool anyB = nW > 32;                     // wave-uniform
    int pA = 0, iA = 0, jA = 0, pB = 0, iB = 0, jB = 0;
    if (actA) { pA = mylist[pidm];      iA = (pA*171) >> 11; jA = pA - iA*N; }
    if (actB) { pB = mylist[32 + pidm]; iB = (pB*171) >> 11; jB = pB - iB*N; }

    // ---- score helpers ----
    auto scoreHalf = [&](int i, int j, const float* __restrict__ att)->float {
        const float* Lj = &bufL[j*STP + sub*32];
        const float* Ri = &bufR[i*STP + sub*32];
        const float* ah = att + sub*32;
        v4f a = z4;
        for (int h=0; h<32; h+=4) {
            v4f a4 = *reinterpret_cast<const v4f*>(&ah[h]);
            v4f xl = *reinterpret_cast<const v4f*>(&Lj[h]);
            v4f xr = *reinterpret_cast<const v4f*>(&Ri[h]);
            v4f s = xl + xr;
            v4f lr = __builtin_elementwise_fma(s4, __builtin_elementwise_min(s, z4),
                                               __builtin_elementwise_max(s, z4));
            a = __builtin_elementwise_fma(a4, lr, a);
        }
        return (a.x + a.y) + (a.z + a.w);
    };
    auto scoreFull = [&](int i, int j, const float* __restrict__ att)->float {
        const float* Lj = &bufL[j*STP];
        const float* Ri = &bufR[i*STP];
        v4f a = z4;
        for (int h=0; h<HID; h+=4) {
            v4f a4 = *reinterpret_cast<const v4f*>(&att[h]);
            v4f xl = *reinterpret_cast<const v4f*>(&Lj[h]);
            v4f xr = *reinterpret_cast<const v4f*>(&Ri[h]);
            v4f s = xl + xr;
            v4f lr = __builtin_elementwise_fma(s4, __builtin_elementwise_min(s, z4),
                                               __builtin_elementwise_max(s, z4));
            a = __builtin_elementwise_fma(a4, lr, a);
        }
        return (a.x + a.y) + (a.z + a.w);
    };

    // ---- GATv2 core: sparse score -> softmax -> aggregate (own 6 rows) ----
    auto gat_core = [&](const float* __restrict__ att, const float* __restrict__ gbias,
                        float* __restrict__ xout, int strideOut, int useSkip) {
        __syncthreads();                           // B1: xl/xr staged by both waves
        {
            float sA = scoreHalf(iA, jA, att);
            sA += __shfl_xor(sA, 32);
            if (actA && sub == 0) pool[pA] = sA;
            if (anyB) {
                float sB = scoreHalf(iB, jB, att);
                sB += __shfl_xor(sB, 32);
                if (actB && sub == 0) pool[pB] = sB;
            }
            if (w == 1 && ovC) pool[myp2] = scoreFull(im2, jm2, att);
        }
        __syncthreads();                           // B2: all scores written
        if (l < 12) {                              // softmax: 2 lanes per own row
            int i  = r0 + (l >> 1);
            int j0 = (l & 1) * 6;
            float ev[6]; float m = -2e9f;
            #pragma unroll
            for (int jj=0; jj<6; jj++) {
                float v = ((rowm >> (j0 + jj)) & 1u) ? pool[i*N + j0 + jj] : -1e9f;
                ev[jj] = v; m = fmaxf(m, v);
            }
            m = fmaxf(m, __shfl_xor(m, 1));
            float sum = 0.f;
            #pragma unroll
            for (int jj=0; jj<6; jj++) { float e = __expf(ev[jj] - m); ev[jj] = e; sum += e; }
            sum += __shfl_xor(sum, 1);
            float inv = 1.0f / sum;
            #pragma unroll
            for (int jj=0; jj<6; jj++) pool[i*N + j0 + jj] = ev[jj] * inv;
        }
        {   // aggregate own 6 rows (pool rows written by own wave -> no barrier)
            float xj[N];
            #pragma unroll
            for (int j=0;j<N;j++) xj[j] = bufL[j*STP + l];
            v4f X0 = {xj[0], xj[1], xj[2],  xj[3]};
            v4f X1 = {xj[4], xj[5], xj[6],  xj[7]};
            v4f X2 = {xj[8], xj[9], xj[10], xj[11]};
            float bias = gbias[l];
            #pragma unroll
            for (int i=0;i<6;i++) {
                const v4f* ep = reinterpret_cast<const v4f*>(&pool[(r0+i)*N]);
                v4f acc = __builtin_elementwise_fma(ep[0], X0,
                          __builtin_elementwise_fma(ep[1], X1, ep[2]*X2));
                float r = bias + ((acc.x + acc.y) + (acc.z + acc.w));
                if (useSkip) r = fmaf(ALPHA, skipv[i], r);
                xout[(r0+i)*strideOut + l] = fmaxf(r, 0.f);
            }
        }
    };

    // ---- MFMA stage (TW): wave w computes matrix matBase+w into bufL/bufR ----
    auto stage_mfma = [&](const float* __restrict__ xin, int strideIn, int matBase) {
        __syncthreads();                           // B3: xin (prev xout) complete
        const int m = l & 15, quad = l >> 4;
        const int mc = (m < N) ? m : 0;
        i4 aF[2];
        #pragma unroll
        for (int kt=0; kt<2; kt++) {
            const float* xp = &xin[mc*strideIn + kt*32 + quad*8];
            v4f lo = *reinterpret_cast<const v4f*>(xp);
            v4f hi = *reinterpret_cast<const v4f*>(xp + 4);
            unsigned u0 = __float_as_uint(lo.x) + 0x8000u, u1 = __float_as_uint(lo.y) + 0x8000u;
            unsigned u2 = __float_as_uint(lo.z) + 0x8000u, u3 = __float_as_uint(lo.w) + 0x8000u;
            unsigned u4 = __float_as_uint(hi.x) + 0x8000u, u5 = __float_as_uint(hi.y) + 0x8000u;
            unsigned u6 = __float_as_uint(hi.z) + 0x8000u, u7 = __float_as_uint(hi.w) + 0x8000u;
            i4 a;
            a.x = (int)__builtin_amdgcn_perm(u1, u0, 0x07060302u);
            a.y = (int)__builtin_amdgcn_perm(u3, u2, 0x07060302u);
            a.z = (int)__builtin_amdgcn_perm(u5, u4, 0x07060302u);
            a.w = (int)__builtin_amdgcn_perm(u7, u6, 0x07060302u);
            aF[kt] = a;
        }
        const i4* bp = reinterpret_cast<const i4*>(wsT + 4096) + (matBase + w)*512;
        v4f acc[4] = {z4, z4, z4, z4};
        #pragma unroll
        for (int nt=0; nt<4; nt++) {
            i4 b0 = bp[nt*64 + l];
            i4 b1 = bp[(4+nt)*64 + l];
            acc[nt] = __builtin_amdgcn_mfma_f32_16x16x32_bf16(as_v8s(aF[0]), as_v8s(b0), acc[nt], 0, 0, 0);
            acc[nt] = __builtin_amdgcn_mfma_f32_16x16x32_bf16(as_v8s(aF[1]), as_v8s(b1), acc[nt], 0, 0, 0);
        }
        float* dst = w ? bufR : bufL;
        if (quad < 3) {
            #pragma unroll
            for (int nt=0; nt<4; nt++) {
                #pragma unroll
                for (int r=0; r<4; r++)
                    dst[(quad*4+r)*STP + nt*16 + m] = acc[nt][r];
            }
        }
    };

    // ---- fp32 VALU stage (fallback when TW=false): wave w does one matrix ----
    auto stage_f32 = [&](const float* __restrict__ xin, int strideIn,
                         const float* __restrict__ wl, const float* __restrict__ wr) {
        __syncthreads();
        const float* wm = w ? wr : wl;
        float* dst = w ? bufR : bufL;
        #pragma unroll
        for (int half=0; half<2; half++) {
            v2f acc[6];
            #pragma unroll
            for (int i=0;i<6;i++) acc[i] = z2;
            for (int c=0;c<HID;c+=4) {
                v2f w01 = (v2f){wm[(c+0)*HID+l], wm[(c+1)*HID+l]};
                v2f w23 = (v2f){wm[(c+2)*HID+l], wm[(c+3)*HID+l]};
                #pragma unroll
                for (int i=0;i<6;i++) {
                    v4f xv = *reinterpret_cast<const v4f*>(&xin[(half*6+i)*strideIn + c]);
                    acc[i] = __builtin_elementwise_fma(xv.xy, w01, acc[i]);
                    acc[i] = __builtin_elementwise_fma(xv.zw, w23, acc[i]);
                }
            }
            #pragma unroll
            for (int i=0;i<6;i++) dst[(half*6+i)*STP + l] = acc[i].x + acc[i].y;
        }
    };

    // ---- GAT layer 1 (cin = 1; x0 = coord z, own rows) ----
    {
        float wlv = g1_wl[l], wrv = g1_wr[l];
        #pragma unroll
        for (int i=0;i<6;i++) {
            float v = coord[(r0+i)*3 + 2];
            bufL[(r0+i)*STP + l] = v * wlv;
            bufR[(r0+i)*STP + l] = v * wrv;
        }
    }
    gat_core(g1_att, g1_b, xB, HID, 0);          // x1 -> xB

    // ---- GAT layer 2 ----
    if (TW) stage_mfma(xB, HID, 0); else stage_f32(xB, HID, g2_wl, g2_wr);
    gat_core(g2_att, g2_b, xB, HID, 0);          // x2 -> xB (persists for L3/L4)

    // ---- GAT layer 3 ----
    if (TW) stage_mfma(xB, HID, 2); else stage_f32(xB, HID, g3_wl, g3_wr);
    gat_core(g3_att, g3_b, bufR, STP, 1);        // x3 -> bufR

    // ---- logits head (own rows; h-split across lane pairs) ----
    if (l < 48) {
        int i   = r0 + (l >> 3);
        int rem = l & 7;
        int c = rem >> 1, sb = rem & 1;
        float acc = 0.f;
        if (TW) {
            const float* lwT = wsT + 16384 + c*HID + sb*32;
            const float* xr  = &bufR[i*STP + sb*32];
            for (int h=0; h<32; h+=4) {
                v4f xv = *reinterpret_cast<const v4f*>(&xr[h]);
                v4f w4 = *reinterpret_cast<const v4f*>(&lwT[h]);
                acc = fmaf(xv.x, w4.x, acc);
                acc = fmaf(xv.y, w4.y, acc);
                acc = fmaf(xv.z, w4.z, acc);
                acc = fmaf(xv.w, w4.w, acc);
            }
        } else {
            for (int h = sb*32; h < sb*32 + 32; h += 4) {
                v4f xv = *reinterpret_cast<const v4f*>(&bufR[i*STP + h]);
                acc = fmaf(xv.x, lab_w[(h+0)*4+c], acc);
                acc = fmaf(xv.y, lab_w[(h+1)*4+c], acc);
                acc = fmaf(xv.z, lab_w[(h+2)*4+c], acc);
                acc = fmaf(xv.w, lab_w[(h+3)*4+c], acc);
            }
        }
        acc += __shfl_xor(acc, 1);
        if (sb == 0) out[OUT2 + (size_t)b*(N*4) + i*4 + c] = acc + lab_b[c];
    }

    // ---- GAT layer 4 ----
    if (TW) stage_mfma(xB, HID, 4); else stage_f32(xB, HID, g4_wl, g4_wr);
    gat_core(g4_att, g4_b, bufR, STP, 1);        // x4 -> bufR

    // ---- values head (own rows; h-split across lane pairs) ----
    if (l < 12) {
        int i  = r0 + (l >> 1);
        int sb = l & 1;
        float acc = 0.f;
        const float* xr = &bufR[i*STP + sb*32];
        const float* wv = val_w + sb*32;
        for (int h=0; h<32; h+=4) {
            v4f xv = *reinterpret_cast<const v4f*>(&xr[h]);
            v4f w4 = *reinterpret_cast<const v4f*>(&wv[h]);
            acc = fmaf(xv.x, w4.x, acc);
            acc = fmaf(xv.y, w4.y, acc);
            acc = fmaf(xv.z, w4.z, acc);
            acc = fmaf(xv.w, w4.w, acc);
        }
        acc += __shfl_xor(acc, 1);
        if (sb == 0) out[OUT3 + (size_t)b*N + i] = acc + val_b[0];
    }
}

extern "C" void kernel_launch(void* const* d_in, const int* in_sizes, int n_in,
                              void* d_out, int out_size, void* d_ws, size_t ws_size,
                              hipStream_t stream) {
    (void)in_sizes; (void)n_in; (void)out_size;
    const bool useT = (ws_size >= (16384 + 256)*sizeof(float));
    if (useT) {
        prep_kernel<<<dim3(113), dim3(64), 0, stream>>>(
            (const float*)d_in[3],
            (const float*)d_in[11], (const float*)d_in[12],
            (const float*)d_in[15], (const float*)d_in[16],
            (const float*)d_in[19], (const float*)d_in[20],
            (const float*)d_in[23],
            (float*)d_ws);
        gae_kernel<true><<<dim3(4096), dim3(128), 0, stream>>>(
            (const float*)d_in[0],
            (const float*)d_in[1],  (const float*)d_in[2],
            (const float*)d_in[3],  (const float*)d_in[4],
            (const float*)d_in[5],  (const float*)d_in[6],
            (const float*)d_in[7],  (const float*)d_in[8],  (const float*)d_in[9],  (const float*)d_in[10],
            (const float*)d_in[11], (const float*)d_in[12], (const float*)d_in[13], (const float*)d_in[14],
            (const float*)d_in[15], (const float*)d_in[16], (const float*)d_in[17], (const float*)d_in[18],
            (const float*)d_in[19], (const float*)d_in[20], (const float*)d_in[21], (const float*)d_in[22],
            (const float*)d_in[23], (const float*)d_in[24],
            (const float*)d_in[25], (const float*)d_in[26],
            (const float*)d_in[27], (const float*)d_in[28],
            (const float*)d_ws,
            (float*)d_out);
    } else {
        gae_kernel<false><<<dim3(4096), dim3(128), 0, stream>>>(
            (const float*)d_in[0],
            (const float*)d_in[1],  (const float*)d_in[2],
            (const float*)d_in[3],  (const float*)d_in[4],
            (const float*)d_in[5],  (const float*)d_in[6],
            (const float*)d_in[7],  (const float*)d_in[8],  (const float*)d_in[9],  (const float*)d_in[10],
            (const float*)d_in[11], (const float*)d_in[12], (const float*)d_in[13], (const float*)d_in[14],
            (const float*)d_in[15], (const float*)d_in[16], (const float*)d_in[17], (const float*)d_in[18],
            (const float*)d_in[19], (const float*)d_in[20], (const float*)d_in[21], (const float*)d_in[22],
            (const float*)d_in[23], (const float*)d_in[24],
            (const float*)d_in[25], (const float*)d_in[26],
            (const float*)d_in[27], (const float*)d_in[28],
            nullptr,
            (float*)d_out);
    }
}

// Round 2
// 171.183 us; speedup vs baseline: 1.2117x; 1.2117x over previous
//
#include <hip/hip_runtime.h>
#include <hip/hip_bf16.h>
#include <math.h>

#define N     12
#define HID   64
#define STP   68     // padded row stride for bufL/bufR (272 B rows, 16B-aligned)
#define SLOPE 0.2f
#define ALPHA 0.1f

typedef float v2f __attribute__((ext_vector_type(2)));
typedef float v4f __attribute__((ext_vector_type(4)));
typedef int   i4  __attribute__((ext_vector_type(4)));
typedef short v8s __attribute__((ext_vector_type(8)));

static __device__ __forceinline__ v8s as_v8s(i4 v) {
    union { i4 a; v8s b; } u; u.a = v; return u.b;
}

// flat output offsets (float32 elements)
#define OUT0 0          // batch[:,:,:4]
#define OUT1 196608     // batch[:,:,4:5]
#define OUT2 245760     // logits
#define OUT3 442368     // values
#define OUT4 491520     // latent

// ws layout identical to previous round (prep_kernel unchanged):
//   [0,4096)       enc_w2 transposed fp32
//   [4096,16384)   6 GAT matrices bf16 B-fragments
//   [16384,16640)  labT fp32
__global__ void prep_kernel(const float* __restrict__ enc_w2,
                            const float* __restrict__ g2_wl, const float* __restrict__ g2_wr,
                            const float* __restrict__ g3_wl, const float* __restrict__ g3_wr,
                            const float* __restrict__ g4_wl, const float* __restrict__ g4_wr,
                            const float* __restrict__ lab_w,
                            float* __restrict__ ws) {
    int t = threadIdx.x;
    int bx = blockIdx.x;
    if (bx < 64) {                       // enc_w2 fp32 transpose
        int c = bx;
        ws[t*64 + c] = enc_w2[c*64 + t];
        return;
    }
    if (bx == 112) {                     // labT
        #pragma unroll
        for (int c = 0; c < 4; c++) ws[16384 + c*64 + t] = lab_w[t*4 + c];
        return;
    }
    int idx = bx - 64;
    int mat = idx >> 3, rem = idx & 7;
    int kt = rem >> 2, nt = rem & 3;
    const float* src;
    switch (mat) {
        case 0: src = g2_wl; break;
        case 1: src = g2_wr; break;
        case 2: src = g3_wl; break;
        case 3: src = g3_wr; break;
        case 4: src = g4_wl; break;
        default: src = g4_wr; break;
    }
    int quad = t >> 4, col = t & 15;
    int n = nt*16 + col;
    unsigned* dst = (unsigned*)(ws + 4096) + mat*2048 + (kt*4+nt)*256 + t*4;
    #pragma unroll
    for (int jp = 0; jp < 4; jp++) {
        int k0 = kt*32 + quad*8 + 2*jp;
        __hip_bfloat16 h0 = __float2bfloat16(src[(k0+0)*64 + n]);
        __hip_bfloat16 h1 = __float2bfloat16(src[(k0+1)*64 + n]);
        unsigned u0 = *(unsigned short*)&h0, u1 = *(unsigned short*)&h1;
        dst[jp] = u0 | (u1 << 16);
    }
}

// R11: 2-wave blocks kept, but NATURAL register allocation.
// R10 post-mortem: __launch_bounds__(128,8) forced a 64-reg unified budget;
// compiler reserved an accum section for MFMA acc[4], left ~32 arch VGPRs,
// spilled ~208 MB/dispatch to scratch (FETCH 1.3->90 MB, WRITE 2.7->118 MB).
// Fix: (128,4) cap (no forced spill; >= R0 occupancy guaranteed), MFMA acc
// split into two acc[2] passes (peak accum 8 regs), pair i/j derived per
// layer from pA/pB instead of carried. Target: alloc <= 64 -> 8 waves/SIMD.
template<bool TW>
__global__ __launch_bounds__(128, 4) void gae_kernel(
    const float* __restrict__ batch,
    const float* __restrict__ enc_w1, const float* __restrict__ enc_b1,
    const float* __restrict__ enc_w2, const float* __restrict__ enc_b2,
    const float* __restrict__ enc_w3, const float* __restrict__ enc_b3,
    const float* __restrict__ g1_wl, const float* __restrict__ g1_wr,
    const float* __restrict__ g1_att, const float* __restrict__ g1_b,
    const float* __restrict__ g2_wl, const float* __restrict__ g2_wr,
    const float* __restrict__ g2_att, const float* __restrict__ g2_b,
    const float* __restrict__ g3_wl, const float* __restrict__ g3_wr,
    const float* __restrict__ g3_att, const float* __restrict__ g3_b,
    const float* __restrict__ g4_wl, const float* __restrict__ g4_wr,
    const float* __restrict__ g4_att, const float* __restrict__ g4_b,
    const float* __restrict__ lab_w, const float* __restrict__ lab_b,
    const float* __restrict__ val_w, const float* __restrict__ val_b,
    const float* __restrict__ skip_w, const float* __restrict__ skip_b,
    const float* __restrict__ wsT,
    float* __restrict__ out)
{
    const int b = blockIdx.x;
    const int t = threadIdx.x;
    const int w = t >> 6;       // wave id (0/1) -- uniform per wave
    const int l = t & 63;       // lane
    const int r0 = w * 6;       // first row owned by this wave

    __shared__ __align__(16) float lds[2544];
    float* bufL  = lds;                          // stride STP, rows 0..11
    float* bufR  = lds + N*STP;                  // stride STP
    float* xB    = lds + 2*N*STP;                // stride HID (x1/x2 storage)
    float* pool  = lds + 2*N*STP + N*HID;        // 144 floats: batch/e-matrix
    float* coord = pool + 108;                   // 36 floats latent coords
    // transient scratch inside pool (dead once e-scores are written):
    //   pool[64..70)  gabriel ballot masks (6 dwords)
    //   pool[72..104) compacted pair lists (64 B per wave)

    const v2f z2 = {0.f, 0.f};
    const v4f z4 = {0.f, 0.f, 0.f, 0.f};
    const v4f s4 = {SLOPE, SLOPE, SLOPE, SLOPE};

    // ---- stage batch (own half) + passthrough outputs 0/1 ----
    if (l < 30) {
        int idx = w*30 + l;
        float v = batch[b*(N*5) + idx];
        pool[idx] = v;
        int i = idx / 5, f = idx - (idx/5)*5;
        if (f < 4) out[OUT0 + (size_t)b*(N*4) + i*4 + f] = v;
        else       out[OUT1 + (size_t)b*N + i] = v;
    }

    // ---- encoder layer 1 (own 6 rows) ----
    {
        float acc[6];
        float bias = enc_b1[l];
        #pragma unroll
        for (int i=0;i<6;i++) acc[i] = bias;
        #pragma unroll
        for (int f=0; f<5; f++) {
            float wv = enc_w1[f*HID + l];
            #pragma unroll
            for (int i=0;i<6;i++) acc[i] = fmaf(pool[(r0+i)*5+f], wv, acc[i]);
        }
        #pragma unroll
        for (int i=0;i<6;i++) bufL[(r0+i)*STP + l] = fmaxf(acc[i], 0.f);
    }

    // ---- encoder layer 2 (own 6 rows; fp32, K-loop ROLLED) ----
    {
        v2f acc[6];
        #pragma unroll
        for (int i=0;i<6;i++) acc[i] = z2;
        const float* w2p = TW ? (wsT + l*HID) : nullptr;
        for (int c=0;c<HID;c+=4) {
            v2f w01, w23;
            if (TW) {
                v4f w4 = *reinterpret_cast<const v4f*>(&w2p[c]);
                w01 = w4.xy; w23 = w4.zw;
            } else {
                w01 = (v2f){enc_w2[(c+0)*HID+l], enc_w2[(c+1)*HID+l]};
                w23 = (v2f){enc_w2[(c+2)*HID+l], enc_w2[(c+3)*HID+l]};
            }
            #pragma unroll
            for (int i=0;i<6;i++) {
                v4f xv = *reinterpret_cast<const v4f*>(&bufL[(r0+i)*STP + c]);
                acc[i] = __builtin_elementwise_fma(xv.xy, w01, acc[i]);
                acc[i] = __builtin_elementwise_fma(xv.zw, w23, acc[i]);
            }
        }
        float bias = enc_b2[l];
        #pragma unroll
        for (int i=0;i<6;i++) bufR[(r0+i)*STP + l] = fmaxf(bias + acc[i].x + acc[i].y, 0.f);
    }

    // ---- latent (own rows; k-dim split across lane pairs) ----
    if (l < 36) {
        int i   = r0 + l/6;
        int rem = l - (l/6)*6;
        int c   = rem >> 1, sb = rem & 1;
        float acc = 0.f;
        for (int k = sb*32; k < sb*32 + 32; k += 4) {
            v4f xv = *reinterpret_cast<const v4f*>(&bufR[i*STP + k]);
            acc = fmaf(xv.x, enc_w3[(k+0)*3+c], acc);
            acc = fmaf(xv.y, enc_w3[(k+1)*3+c], acc);
            acc = fmaf(xv.z, enc_w3[(k+2)*3+c], acc);
            acc = fmaf(xv.w, enc_w3[(k+3)*3+c], acc);
        }
        acc += __shfl_xor(acc, 1);
        if (sb == 0) {
            acc += enc_b3[c];
            coord[i*3 + c] = acc;
            out[OUT4 + (size_t)b*(N*3) + i*3 + c] = acc;
        }
    }

    // ---- skip connection (own rows, own-wave coords) -> registers ----
    float skipv[6];
    {
        float w0 = skip_w[l], w1 = skip_w[HID+l], w2v = skip_w[2*HID+l];
        float bias = skip_b[l];
        #pragma unroll
        for (int i=0;i<6;i++) {
            float v = bias;
            v = fmaf(coord[(r0+i)*3+0], w0, v);
            v = fmaf(coord[(r0+i)*3+1], w1, v);
            v = fmaf(coord[(r0+i)*3+2], w2v, v);
            skipv[i] = v;
        }
    }
    __syncthreads();   // B0: all coords visible

    // ---- Gabriel adjacency (wave0: pairs 0-63; wave1: 64-127 + 128-143) ----
    auto gab = [&](int i, int j)->bool {
        if (i == j) return false;
        float pix = coord[i*3], piy = coord[i*3+1];
        float pjx = coord[j*3], pjy = coord[j*3+1];
        float mx = (pix + pjx) * 0.5f, my = (piy + pjy) * 0.5f;
        float dx = pix - pjx, dy = piy - pjy;
        float r2 = (dx*dx + dy*dy) * 0.25f;
        bool g = true;
        #pragma unroll
        for (int k=0;k<N;k++) {
            float ex = coord[k*3] - mx, ey = coord[k*3+1] - my;
            bool ok = (k == i) || (k == j) || (ex*ex + ey*ey > r2);
            g = g && ok;
        }
        return g;
    };
    unsigned* pu = (unsigned*)(pool + 64);
    if (w == 0) {
        int i0 = (l*171) >> 11, j0 = l - i0*N;
        unsigned long long m0 = __ballot(gab(i0, j0));
        if (l == 0) { pu[0] = (unsigned)m0; pu[1] = (unsigned)(m0 >> 32); }
    } else {
        int p1 = 64 + l;
        int i1 = (p1*171) >> 11, j1 = p1 - i1*N;
        unsigned long long m1 = __ballot(gab(i1, j1));
        int p2 = (l < 16) ? (128 + l) : 143;
        int i2 = (p2*171) >> 11, j2 = p2 - i2*N;
        unsigned long long m2 = __ballot((l < 16) && gab(i2, j2));
        if (l == 0) { pu[2] = (unsigned)m1; pu[3] = (unsigned)(m1 >> 32);
                      pu[4] = (unsigned)m2; pu[5] = (unsigned)(m2 >> 32); }
    }
    __syncthreads();   // B0b: masks visible

    const unsigned long long gb0 = (unsigned long long)pu[0] | ((unsigned long long)pu[1] << 32);
    const unsigned long long gb1 = (unsigned long long)pu[2] | ((unsigned long long)pu[3] << 32);
    const unsigned long long gb2 = (unsigned long long)pu[4] | ((unsigned long long)pu[5] << 32);
    auto gbit = [&](int p)->int {
        unsigned long long m = (p < 64) ? gb0 : ((p < 128) ? gb1 : gb2);
        return (int)((m >> (p & 63)) & 1ull);
    };
    auto mbcnt64 = [&](unsigned long long m)->int {
        return __builtin_amdgcn_mbcnt_hi((unsigned)(m >> 32),
               __builtin_amdgcn_mbcnt_lo((unsigned)m, 0));
    };

    // ---- per-row adjacency mask for softmax (2 lanes per row) ----
    unsigned rowm = 0;
    if (l < 12) {
        int ri = r0 + (l >> 1);
        #pragma unroll
        for (int j=0;j<N;j++)
            rowm |= (unsigned)(gbit(ri*N + j) | gbit(j*N + ri) | (ri == j)) << j;
    }

    // ---- compact valid pairs (per-wave list, per-wave slots) ----
    int nW = 0;
    bool ovC = false; int myp2 = 0;
    unsigned char* mylist = (unsigned char*)(pool + 72) + w*64;
    if (w == 0) {
        int i0 = (l*171) >> 11, j0 = l - i0*N;
        int a = gbit(l) | gbit(j0*N + i0) | (i0 == j0);
        unsigned long long am = __ballot(a != 0);
        if (a) mylist[mbcnt64(am)] = (unsigned char)l;
        nW = __popcll(am);                         // <= 64, never overflows
    } else {
        int p1 = 64 + l;
        int i1 = (p1*171) >> 11, j1 = p1 - i1*N;
        int aB = gbit(p1) | gbit(j1*N + i1) | (i1 == j1);
        int p2 = (l < 16) ? (128 + l) : 143;
        int i2 = (p2*171) >> 11, j2 = p2 - i2*N;
        int aC = (l < 16) ? (gbit(p2) | gbit(j2*N + i2) | (i2 == j2)) : 0;
        unsigned long long am1 = __ballot(aB != 0);
        unsigned long long am2 = __ballot(aC != 0);
        int c1 = __popcll(am1);
        int idx1 = mbcnt64(am1);
        int idx2 = c1 + mbcnt64(am2);
        if (aB) mylist[idx1] = (unsigned char)p1;
        if (aC && idx2 < 64) mylist[idx2] = (unsigned char)p2;
        ovC = aC && (idx2 >= 64);                  // rare (planarity: total <= ~68)
        myp2 = p2;
        int n = c1 + __popcll(am2);
        nW = n < 64 ? n : 64;
    }
    // score assignment: 2 lanes per pair (h-dim split), up to 2 passes of 32.
    // Only pA/pB carried across layers; i/j derived per layer (3 VALU each).
    const int pidm = l & 31, sub = l >> 5;
    const bool actA = pidm < nW;
    const bool actB = (32 + pidm) < nW;
    const bool anyB = nW > 32;                     // wave-uniform
    int pA = 0, pB = 0;
    if (actA) pA = mylist[pidm];
    if (actB) pB = mylist[32 + pidm];

    // ---- score helpers ----
    auto scoreHalf = [&](int i, int j, const float* __restrict__ att)->float {
        const float* Lj = &bufL[j*STP + sub*32];
        const float* Ri = &bufR[i*STP + sub*32];
        const float* ah = att + sub*32;
        v4f a = z4;
        for (int h=0; h<32; h+=4) {
            v4f a4 = *reinterpret_cast<const v4f*>(&ah[h]);
            v4f xl = *reinterpret_cast<const v4f*>(&Lj[h]);
            v4f xr = *reinterpret_cast<const v4f*>(&Ri[h]);
            v4f s = xl + xr;
            v4f lr = __builtin_elementwise_fma(s4, __builtin_elementwise_min(s, z4),
                                               __builtin_elementwise_max(s, z4));
            a = __builtin_elementwise_fma(a4, lr, a);
        }
        return (a.x + a.y) + (a.z + a.w);
    };
    auto scoreFull = [&](int i, int j, const float* __restrict__ att)->float {
        const float* Lj = &bufL[j*STP];
        const float* Ri = &bufR[i*STP];
        v4f a = z4;
        for (int h=0; h<HID; h+=4) {
            v4f a4 = *reinterpret_cast<const v4f*>(&att[h]);
            v4f xl = *reinterpret_cast<const v4f*>(&Lj[h]);
            v4f xr = *reinterpret_cast<const v4f*>(&Ri[h]);
            v4f s = xl + xr;
            v4f lr = __builtin_elementwise_fma(s4, __builtin_elementwise_min(s, z4),
                                               __builtin_elementwise_max(s, z4));
            a = __builtin_elementwise_fma(a4, lr, a);
        }
        return (a.x + a.y) + (a.z + a.w);
    };

    // ---- GATv2 core: sparse score -> softmax -> aggregate (own 6 rows) ----
    auto gat_core = [&](const float* __restrict__ att, const float* __restrict__ gbias,
                        float* __restrict__ xout, int strideOut, int useSkip) {
        __syncthreads();                           // B1: xl/xr staged by both waves
        {
            int iA = (pA*171) >> 11, jA = pA - iA*N;
            float sA = scoreHalf(iA, jA, att);
            sA += __shfl_xor(sA, 32);
            if (actA && sub == 0) pool[pA] = sA;
            if (anyB) {
                int iB = (pB*171) >> 11, jB = pB - iB*N;
                float sB = scoreHalf(iB, jB, att);
                sB += __shfl_xor(sB, 32);
                if (actB && sub == 0) pool[pB] = sB;
            }
            if (w == 1 && ovC) {
                int i2 = (myp2*171) >> 11, j2 = myp2 - i2*N;
                pool[myp2] = scoreFull(i2, j2, att);
            }
        }
        __syncthreads();                           // B2: all scores written
        if (l < 12) {                              // softmax: 2 lanes per own row
            int i  = r0 + (l >> 1);
            int j0 = (l & 1) * 6;
            float ev[6]; float m = -2e9f;
            #pragma unroll
            for (int jj=0; jj<6; jj++) {
                float v = ((rowm >> (j0 + jj)) & 1u) ? pool[i*N + j0 + jj] : -1e9f;
                ev[jj] = v; m = fmaxf(m, v);
            }
            m = fmaxf(m, __shfl_xor(m, 1));
            float sum = 0.f;
            #pragma unroll
            for (int jj=0; jj<6; jj++) { float e = __expf(ev[jj] - m); ev[jj] = e; sum += e; }
            sum += __shfl_xor(sum, 1);
            float inv = 1.0f / sum;
            #pragma unroll
            for (int jj=0; jj<6; jj++) pool[i*N + j0 + jj] = ev[jj] * inv;
        }
        {   // aggregate own 6 rows (pool rows written by own wave -> no barrier)
            float xj[N];
            #pragma unroll
            for (int j=0;j<N;j++) xj[j] = bufL[j*STP + l];
            v4f X0 = {xj[0], xj[1], xj[2],  xj[3]};
            v4f X1 = {xj[4], xj[5], xj[6],  xj[7]};
            v4f X2 = {xj[8], xj[9], xj[10], xj[11]};
            float bias = gbias[l];
            #pragma unroll
            for (int i=0;i<6;i++) {
                const v4f* ep = reinterpret_cast<const v4f*>(&pool[(r0+i)*N]);
                v4f acc = __builtin_elementwise_fma(ep[0], X0,
                          __builtin_elementwise_fma(ep[1], X1, ep[2]*X2));
                float r = bias + ((acc.x + acc.y) + (acc.z + acc.w));
                if (useSkip) r = fmaf(ALPHA, skipv[i], r);
                xout[(r0+i)*strideOut + l] = fmaxf(r, 0.f);
            }
        }
    };

    // ---- MFMA stage (TW): wave w computes matrix matBase+w into bufL/bufR.
    //      Two passes of acc[2] to keep peak accum pressure at 8 regs. ----
    auto stage_mfma = [&](const float* __restrict__ xin, int strideIn, int matBase) {
        __syncthreads();                           // B3: xin (prev xout) complete
        const int m = l & 15, quad = l >> 4;
        const int mc = (m < N) ? m : 0;
        i4 aF[2];
        #pragma unroll
        for (int kt=0; kt<2; kt++) {
            const float* xp = &xin[mc*strideIn + kt*32 + quad*8];
            v4f lo = *reinterpret_cast<const v4f*>(xp);
            v4f hi = *reinterpret_cast<const v4f*>(xp + 4);
            unsigned u0 = __float_as_uint(lo.x) + 0x8000u, u1 = __float_as_uint(lo.y) + 0x8000u;
            unsigned u2 = __float_as_uint(lo.z) + 0x8000u, u3 = __float_as_uint(lo.w) + 0x8000u;
            unsigned u4 = __float_as_uint(hi.x) + 0x8000u, u5 = __float_as_uint(hi.y) + 0x8000u;
            unsigned u6 = __float_as_uint(hi.z) + 0x8000u, u7 = __float_as_uint(hi.w) + 0x8000u;
            i4 a;
            a.x = (int)__builtin_amdgcn_perm(u1, u0, 0x07060302u);
            a.y = (int)__builtin_amdgcn_perm(u3, u2, 0x07060302u);
            a.z = (int)__builtin_amdgcn_perm(u5, u4, 0x07060302u);
            a.w = (int)__builtin_amdgcn_perm(u7, u6, 0x07060302u);
            aF[kt] = a;
        }
        const i4* bp = reinterpret_cast<const i4*>(wsT + 4096) + (matBase + w)*512;
        float* dst = w ? bufR : bufL;
        #pragma unroll
        for (int ph=0; ph<2; ph++) {
            v4f acc[2] = {z4, z4};
            #pragma unroll
            for (int q=0; q<2; q++) {
                int nt = ph*2 + q;
                i4 b0 = bp[nt*64 + l];
                i4 b1 = bp[(4+nt)*64 + l];
                acc[q] = __builtin_amdgcn_mfma_f32_16x16x32_bf16(as_v8s(aF[0]), as_v8s(b0), acc[q], 0, 0, 0);
                acc[q] = __builtin_amdgcn_mfma_f32_16x16x32_bf16(as_v8s(aF[1]), as_v8s(b1), acc[q], 0, 0, 0);
            }
            if (quad < 3) {
                #pragma unroll
                for (int q=0; q<2; q++) {
                    int nt = ph*2 + q;
                    #pragma unroll
                    for (int r=0; r<4; r++)
                        dst[(quad*4+r)*STP + nt*16 + m] = acc[q][r];
                }
            }
        }
    };

    // ---- fp32 VALU stage (fallback when TW=false): wave w does one matrix ----
    auto stage_f32 = [&](const float* __restrict__ xin, int strideIn,
                         const float* __restrict__ wl, const float* __restrict__ wr) {
        __syncthreads();
        const float* wm = w ? wr : wl;
        float* dst = w ? bufR : bufL;
        #pragma unroll
        for (int half=0; half<2; half++) {
            v2f acc[6];
            #pragma unroll
            for (int i=0;i<6;i++) acc[i] = z2;
            for (int c=0;c<HID;c+=4) {
                v2f w01 = (v2f){wm[(c+0)*HID+l], wm[(c+1)*HID+l]};
                v2f w23 = (v2f){wm[(c+2)*HID+l], wm[(c+3)*HID+l]};
                #pragma unroll
                for (int i=0;i<6;i++) {
                    v4f xv = *reinterpret_cast<const v4f*>(&xin[(half*6+i)*strideIn + c]);
                    acc[i] = __builtin_elementwise_fma(xv.xy, w01, acc[i]);
                    acc[i] = __builtin_elementwise_fma(xv.zw, w23, acc[i]);
                }
            }
            #pragma unroll
            for (int i=0;i<6;i++) dst[(half*6+i)*STP + l] = acc[i].x + acc[i].y;
        }
    };

    // ---- GAT layer 1 (cin = 1; x0 = coord z, own rows) ----
    {
        float wlv = g1_wl[l], wrv = g1_wr[l];
        #pragma unroll
        for (int i=0;i<6;i++) {
            float v = coord[(r0+i)*3 + 2];
            bufL[(r0+i)*STP + l] = v * wlv;
            bufR[(r0+i)*STP + l] = v * wrv;
        }
    }
    gat_core(g1_att, g1_b, xB, HID, 0);          // x1 -> xB

    // ---- GAT layer 2 ----
    if (TW) stage_mfma(xB, HID, 0); else stage_f32(xB, HID, g2_wl, g2_wr);
    gat_core(g2_att, g2_b, xB, HID, 0);          // x2 -> xB (persists for L3/L4)

    // ---- GAT layer 3 ----
    if (TW) stage_mfma(xB, HID, 2); else stage_f32(xB, HID, g3_wl, g3_wr);
    gat_core(g3_att, g3_b, bufR, STP, 1);        // x3 -> bufR

    // ---- logits head (own rows; h-split across lane pairs) ----
    if (l < 48) {
        int i   = r0 + (l >> 3);
        int rem = l & 7;
        int c = rem >> 1, sb = rem & 1;
        float acc = 0.f;
        if (TW) {
            const float* lwT = wsT + 16384 + c*HID + sb*32;
            const float* xr  = &bufR[i*STP + sb*32];
            for (int h=0; h<32; h+=4) {
                v4f xv = *reinterpret_cast<const v4f*>(&xr[h]);
                v4f w4 = *reinterpret_cast<const v4f*>(&lwT[h]);
                acc = fmaf(xv.x, w4.x, acc);
                acc = fmaf(xv.y, w4.y, acc);
                acc = fmaf(xv.z, w4.z, acc);
                acc = fmaf(xv.w, w4.w, acc);
            }
        } else {
            for (int h = sb*32; h < sb*32 + 32; h += 4) {
                v4f xv = *reinterpret_cast<const v4f*>(&bufR[i*STP + h]);
                acc = fmaf(xv.x, lab_w[(h+0)*4+c], acc);
                acc = fmaf(xv.y, lab_w[(h+1)*4+c], acc);
                acc = fmaf(xv.z, lab_w[(h+2)*4+c], acc);
                acc = fmaf(xv.w, lab_w[(h+3)*4+c], acc);
            }
        }
        acc += __shfl_xor(acc, 1);
        if (sb == 0) out[OUT2 + (size_t)b*(N*4) + i*4 + c] = acc + lab_b[c];
    }

    // ---- GAT layer 4 ----
    if (TW) stage_mfma(xB, HID, 4); else stage_f32(xB, HID, g4_wl, g4_wr);
    gat_core(g4_att, g4_b, bufR, STP, 1);        // x4 -> bufR

    // ---- values head (own rows; h-split across lane pairs) ----
    if (l < 12) {
        int i  = r0 + (l >> 1);
        int sb = l & 1;
        float acc = 0.f;
        const float* xr = &bufR[i*STP + sb*32];
        const float* wv = val_w + sb*32;
        for (int h=0; h<32; h+=4) {
            v4f xv = *reinterpret_cast<const v4f*>(&xr[h]);
            v4f w4 = *reinterpret_cast<const v4f*>(&wv[h]);
            acc = fmaf(xv.x, w4.x, acc);
            acc = fmaf(xv.y, w4.y, acc);
            acc = fmaf(xv.z, w4.z, acc);
            acc = fmaf(xv.w, w4.w, acc);
        }
        acc += __shfl_xor(acc, 1);
        if (sb == 0) out[OUT3 + (size_t)b*N + i] = acc + val_b[0];
    }
}

extern "C" void kernel_launch(void* const* d_in, const int* in_sizes, int n_in,
                              void* d_out, int out_size, void* d_ws, size_t ws_size,
                              hipStream_t stream) {
    (void)in_sizes; (void)n_in; (void)out_size;
    const bool useT = (ws_size >= (16384 + 256)*sizeof(float));
    if (useT) {
        prep_kernel<<<dim3(113), dim3(64), 0, stream>>>(
            (const float*)d_in[3],
            (const float*)d_in[11], (const float*)d_in[12],
            (const float*)d_in[15], (const float*)d_in[16],
            (const float*)d_in[19], (const float*)d_in[20],
            (const float*)d_in[23],
            (float*)d_ws);
        gae_kernel<true><<<dim3(4096), dim3(128), 0, stream>>>(
            (const float*)d_in[0],
            (const float*)d_in[1],  (const float*)d_in[2],
            (const float*)d_in[3],  (const float*)d_in[4],
            (const float*)d_in[5],  (const float*)d_in[6],
            (const float*)d_in[7],  (const float*)d_in[8],  (const float*)d_in[9],  (const float*)d_in[10],
            (const float*)d_in[11], (const float*)d_in[12], (const float*)d_in[13], (const float*)d_in[14],
            (const float*)d_in[15], (const float*)d_in[16], (const float*)d_in[17], (const float*)d_in[18],
            (const float*)d_in[19], (const float*)d_in[20], (const float*)d_in[21], (const float*)d_in[22],
            (const float*)d_in[23], (const float*)d_in[24],
            (const float*)d_in[25], (const float*)d_in[26],
            (const float*)d_in[27], (const float*)d_in[28],
            (const float*)d_ws,
            (float*)d_out);
    } else {
        gae_kernel<false><<<dim3(4096), dim3(128), 0, stream>>>(
            (const float*)d_in[0],
            (const float*)d_in[1],  (const float*)d_in[2],
            (const float*)d_in[3],  (const float*)d_in[4],
            (const float*)d_in[5],  (const float*)d_in[6],
            (const float*)d_in[7],  (const float*)d_in[8],  (const float*)d_in[9],  (const float*)d_in[10],
            (const float*)d_in[11], (const float*)d_in[12], (const float*)d_in[13], (const float*)d_in[14],
            (const float*)d_in[15], (const float*)d_in[16], (const float*)d_in[17], (const float*)d_in[18],
            (const float*)d_in[19], (const float*)d_in[20], (const float*)d_in[21], (const float*)d_in[22],
            (const float*)d_in[23], (const float*)d_in[24],
            (const float*)d_in[25], (const float*)d_in[26],
            (const float*)d_in[27], (const float*)d_in[28],
            nullptr,
            (float*)d_out);
    }
}

// Round 3
// 159.152 us; speedup vs baseline: 1.3033x; 1.0756x over previous
//
#include <hip/hip_runtime.h>
#include <hip/hip_bf16.h>
#include <math.h>

#define N     12
#define HID   64
#define STP   68     // padded row stride for bufL/bufR (272 B rows, 16B-aligned)
#define SLOPE 0.2f
#define ALPHA 0.1f

typedef float v2f __attribute__((ext_vector_type(2)));
typedef float v4f __attribute__((ext_vector_type(4)));
typedef int   i4  __attribute__((ext_vector_type(4)));
typedef short v8s __attribute__((ext_vector_type(8)));

static __device__ __forceinline__ v8s as_v8s(i4 v) {
    union { i4 a; v8s b; } u; u.a = v; return u.b;
}

// flat output offsets (float32 elements)
#define OUT0 0          // batch[:,:,:4]
#define OUT1 196608     // batch[:,:,4:5]
#define OUT2 245760     // logits
#define OUT3 442368     // values
#define OUT4 491520     // latent

// ws layout (float offsets):
//   [0,4096)         enc_w2 transposed fp32
//   [4096,16384)     6 GAT matrices bf16 B-fragments
//   [16384,16640)    labT fp32
__global__ void prep_kernel(const float* __restrict__ enc_w2,
                            const float* __restrict__ g2_wl, const float* __restrict__ g2_wr,
                            const float* __restrict__ g3_wl, const float* __restrict__ g3_wr,
                            const float* __restrict__ g4_wl, const float* __restrict__ g4_wr,
                            const float* __restrict__ lab_w,
                            float* __restrict__ ws) {
    int t = threadIdx.x;
    int bx = blockIdx.x;
    if (bx < 64) {                       // enc_w2 fp32 transpose
        int c = bx;
        ws[t*64 + c] = enc_w2[c*64 + t];
        return;
    }
    if (bx == 112) {                     // labT
        #pragma unroll
        for (int c = 0; c < 4; c++) ws[16384 + c*64 + t] = lab_w[t*4 + c];
        return;
    }
    // B-fragment pack: 48 blocks = 6 matrices x 2 kt x 4 nt
    int idx = bx - 64;
    int mat = idx >> 3, rem = idx & 7;
    int kt = rem >> 2, nt = rem & 3;
    const float* src;
    switch (mat) {
        case 0: src = g2_wl; break;
        case 1: src = g2_wr; break;
        case 2: src = g3_wl; break;
        case 3: src = g3_wr; break;
        case 4: src = g4_wl; break;
        default: src = g4_wr; break;
    }
    int quad = t >> 4, col = t & 15;
    int n = nt*16 + col;
    unsigned* dst = (unsigned*)(ws + 4096) + mat*2048 + (kt*4+nt)*256 + t*4;
    #pragma unroll
    for (int jp = 0; jp < 4; jp++) {
        int k0 = kt*32 + quad*8 + 2*jp;
        __hip_bfloat16 h0 = __float2bfloat16(src[(k0+0)*64 + n]);
        __hip_bfloat16 h1 = __float2bfloat16(src[(k0+1)*64 + n]);
        unsigned u0 = *(unsigned short*)&h0, u1 = *(unsigned short*)&h1;
        dst[jp] = u0 | (u1 << 16);
    }
}

// R12: back to the verified 1-wave structure (R10/R11 showed multi-wave blocks
// convoy on barriers: 88-111 us vs 47.8). R0 counters: VALUBusy 44% with 4
// waves/SIMD -> per-wave issue duty ~11%, stalled ~89% on dependent-load
// chains in the ROLLED 16-iter K-loops. Occupancy is GRID-capped (4096 waves
// = 4/SIMD), so VGPRs up to 128 are free (512/128=4): spend them on ILP.
// Change vs R0: partial unroll (x4; full on scoreAt) of enc2/latent/score/
// head loops -> 4-16 outstanding loads per loop instead of 1.
// __launch_bounds__(64,4) caps alloc at 128 VGPR (no spill possible).
template<bool TW>
__global__ __launch_bounds__(64, 4) void gae_kernel(
    const float* __restrict__ batch,
    const float* __restrict__ enc_w1, const float* __restrict__ enc_b1,
    const float* __restrict__ enc_w2, const float* __restrict__ enc_b2,
    const float* __restrict__ enc_w3, const float* __restrict__ enc_b3,
    const float* __restrict__ g1_wl, const float* __restrict__ g1_wr,
    const float* __restrict__ g1_att, const float* __restrict__ g1_b,
    const float* __restrict__ g2_wl, const float* __restrict__ g2_wr,
    const float* __restrict__ g2_att, const float* __restrict__ g2_b,
    const float* __restrict__ g3_wl, const float* __restrict__ g3_wr,
    const float* __restrict__ g3_att, const float* __restrict__ g3_b,
    const float* __restrict__ g4_wl, const float* __restrict__ g4_wr,
    const float* __restrict__ g4_att, const float* __restrict__ g4_b,
    const float* __restrict__ lab_w, const float* __restrict__ lab_b,
    const float* __restrict__ val_w, const float* __restrict__ val_b,
    const float* __restrict__ skip_w, const float* __restrict__ skip_b,
    const float* __restrict__ wsT,
    float* __restrict__ out)
{
    const int b = blockIdx.x;
    const int t = threadIdx.x;

    __shared__ __align__(16) float lds[2560];
    float* bufL = lds;                         // stride STP
    float* bufR = lds + N*STP;                 // stride STP
    float* xB   = lds + 2*N*STP;               // stride HID (broadcast-read only)
    float* pool = lds + 2*N*STP + N*HID;       // batch(60)->lat(36)->e(144)
    unsigned char* pairs8 = (unsigned char*)&lds[2544];  // 64 B compacted pair list

    const v2f z2 = {0.f, 0.f};
    const v4f z4 = {0.f, 0.f, 0.f, 0.f};
    const v4f s4 = {SLOPE, SLOPE, SLOPE, SLOPE};

    // score-pair decomposition (144 pairs, 3 slots of 64/64/16)
    const int p0 = t,        i0 = p0 / N, j0 = p0 - i0*N;
    const int p1 = t + 64,   i1 = p1 / N, j1 = p1 - i1*N;
    const int p2 = (t < 16) ? (t + 128) : 143;
    const int i2 = p2 / N,   j2 = p2 - i2*N;

    // ---- stage batch into pool, emit passthrough outputs 0/1 ----
    if (t < N*5) {
        float v = batch[b*(N*5) + t];
        pool[t] = v;
        int i = t / 5, f = t - i*5;
        if (f < 4) out[OUT0 + (size_t)b*(N*4) + i*4 + f] = v;
        else       out[OUT1 + (size_t)b*N + i] = v;
    }
    __syncthreads();

    // ---- encoder layer 1 ----
    {
        float acc[N];
        float bias = enc_b1[t];
        #pragma unroll
        for (int i=0;i<N;i++) acc[i] = bias;
        #pragma unroll
        for (int f=0; f<5; f++) {
            float w = enc_w1[f*HID + t];
            #pragma unroll
            for (int i=0;i<N;i++) acc[i] = fmaf(pool[i*5+f], w, acc[i]);
        }
        #pragma unroll
        for (int i=0;i<N;i++) bufL[i*STP + t] = fmaxf(acc[i], 0.f);
    }
    __syncthreads();

    // ---- encoder layer 2 (fp32; unroll-4 for outstanding loads) ----
    {
        v2f acc[N];
        #pragma unroll
        for (int i=0;i<N;i++) acc[i] = z2;
        const float* w2p = TW ? (wsT + t*HID) : nullptr;
        #pragma unroll 4
        for (int c=0;c<HID;c+=4) {
            v2f w01, w23;
            if (TW) {
                v4f w4 = *reinterpret_cast<const v4f*>(&w2p[c]);
                w01 = w4.xy; w23 = w4.zw;
            } else {
                w01 = (v2f){enc_w2[(c+0)*HID+t], enc_w2[(c+1)*HID+t]};
                w23 = (v2f){enc_w2[(c+2)*HID+t], enc_w2[(c+3)*HID+t]};
            }
            #pragma unroll
            for (int i=0;i<N;i++) {
                v4f xv = *reinterpret_cast<const v4f*>(&bufL[i*STP + c]);
                acc[i] = __builtin_elementwise_fma(xv.xy, w01, acc[i]);
                acc[i] = __builtin_elementwise_fma(xv.zw, w23, acc[i]);
            }
        }
        float bias = enc_b2[t];
        #pragma unroll
        for (int i=0;i<N;i++) bufR[i*STP + t] = fmaxf(bias + acc[i].x + acc[i].y, 0.f);
    }
    __syncthreads();

    // ---- latent = h2 @ W3 + b3 (lanes 0..35) -> pool[0..35] ----
    if (t < N*3) {
        int i = t / 3, c = t - i*3;
        float acc = enc_b3[c];
        #pragma unroll 4
        for (int k=0;k<HID;k+=4) {
            v4f xv = *reinterpret_cast<const v4f*>(&bufR[i*STP + k]);
            acc = fmaf(xv.x, enc_w3[(k+0)*3+c], acc);
            acc = fmaf(xv.y, enc_w3[(k+1)*3+c], acc);
            acc = fmaf(xv.z, enc_w3[(k+2)*3+c], acc);
            acc = fmaf(xv.w, enc_w3[(k+3)*3+c], acc);
        }
        pool[t] = acc;
        out[OUT4 + (size_t)b*(N*3) + t] = acc;
    }
    __syncthreads();

    // ---- skip connection -> registers ----
    float skipv[N];
    {
        float w0 = skip_w[t], w1 = skip_w[HID+t], w2 = skip_w[2*HID+t];
        float bias = skip_b[t];
        #pragma unroll
        for (int i=0;i<N;i++) {
            float v = bias;
            v = fmaf(pool[i*3+0], w0, v);
            v = fmaf(pool[i*3+1], w1, v);
            v = fmaf(pool[i*3+2], w2, v);
            skipv[i] = v;
        }
    }

    // ---- Gabriel adjacency via ballots ----
    auto gab = [&](int i, int j)->bool {
        if (i == j) return false;
        float pix = pool[i*3], piy = pool[i*3+1];
        float pjx = pool[j*3], pjy = pool[j*3+1];
        float mx = (pix + pjx) * 0.5f, my = (piy + pjy) * 0.5f;
        float dx = pix - pjx, dy = piy - pjy;
        float r2 = (dx*dx + dy*dy) * 0.25f;
        bool g = true;
        #pragma unroll
        for (int k=0;k<N;k++) {
            float ex = pool[k*3] - mx, ey = pool[k*3+1] - my;
            bool ok = (k == i) || (k == j) || (ex*ex + ey*ey > r2);
            g = g && ok;
        }
        return g;
    };
    unsigned long long gb0 = __ballot(gab(i0, j0));
    unsigned long long gb1 = __ballot(gab(i1, j1));
    unsigned long long gb2 = __ballot((t < 16) && gab(i2, j2));
    auto gbit = [&](int p)->int {
        unsigned long long m = (p < 64) ? gb0 : ((p < 128) ? gb1 : gb2);
        return (int)((m >> (p & 63)) & 1ull);
    };
    const int adjA = gbit(p0) | gbit(j0*N+i0) | (i0 == j0);
    const int adjB = gbit(p1) | gbit(j1*N+i1) | (i1 == j1);
    const int adjC = (t < 16) ? (gbit(p2) | gbit(j2*N+i2) | (i2 == j2)) : 0;

    // ---- compact valid pairs ----
    auto mbcnt64 = [&](unsigned long long m)->int {
        return __builtin_amdgcn_mbcnt_hi((unsigned)(m >> 32),
               __builtin_amdgcn_mbcnt_lo((unsigned)m, 0));
    };
    const unsigned long long am0 = __ballot(adjA != 0);
    const unsigned long long am1 = __ballot(adjB != 0);
    const unsigned long long am2 = __ballot(adjC != 0);
    const int c0  = __popcll(am0);
    const int c01 = c0 + __popcll(am1);
    const int nv  = c01 + __popcll(am2);
    const int idx0 = mbcnt64(am0);
    const int idx1 = c0  + mbcnt64(am1);
    const int idx2 = c01 + mbcnt64(am2);
    if (adjA)               pairs8[idx0] = (unsigned char)p0;
    if (adjB && idx1 < 64)  pairs8[idx1] = (unsigned char)p1;
    if (adjC && idx2 < 64)  pairs8[idx2] = (unsigned char)p2;
    const bool ovB = adjB && (idx1 >= 64);
    const bool ovC = adjC && (idx2 >= 64);
    const int nvc = nv < 64 ? nv : 64;

    // ---- score for one adjacent pair (FULL unroll: all att/LDS loads can
    //      issue ahead; accumulator chain order unchanged) ----
    auto scoreAt = [&](int i, int j, const float* __restrict__ att)->float {
        const float* Lj = &bufL[j*STP];
        const float* Ri = &bufR[i*STP];
        v4f a = z4;
        #pragma unroll
        for (int h=0; h<HID; h+=4) {
            v4f a4 = *reinterpret_cast<const v4f*>(&att[h]);
            v4f xl = *reinterpret_cast<const v4f*>(Lj + h);
            v4f xr = *reinterpret_cast<const v4f*>(Ri + h);
            v4f s = xl + xr;
            v4f l = __builtin_elementwise_fma(s4, __builtin_elementwise_min(s, z4),
                                              __builtin_elementwise_max(s, z4));
            a = __builtin_elementwise_fma(a4, l, a);
        }
        return (a.x + a.y) + (a.z + a.w);
    };

    // ---- GATv2 core: sparse score -> softmax -> aggregate ----
    auto gat_core = [&](const float* __restrict__ att, const float* __restrict__ gb,
                        float* __restrict__ xout, int strideOut, int useSkip) {
        __syncthreads();
        pool[t] = -1e9f; pool[t+64] = -1e9f;
        if (t < 16) pool[t+128] = -1e9f;
        if (t < nvc) {
            int p = pairs8[t];
            int i = (p * 171) >> 11;           // p/12 for p<144
            int j = p - i*N;
            pool[p] = scoreAt(i, j, att);
        }
        if (nv > 64) {
            if (ovB) pool[p1] = scoreAt(i1, j1, att);
            if (ovC) pool[p2] = scoreAt(i2, j2, att);
        }
        __syncthreads();
        if (t < N) {   // row softmax
            float m = -2e9f;
            #pragma unroll
            for (int j=0;j<N;j++) m = fmaxf(m, pool[t*N+j]);
            float tmp[N]; float sum = 0.f;
            #pragma unroll
            for (int j=0;j<N;j++) { float v = __expf(pool[t*N+j] - m); tmp[j] = v; sum += v; }
            float inv = 1.0f / sum;
            #pragma unroll
            for (int j=0;j<N;j++) pool[t*N+j] = tmp[j] * inv;
        }
        __syncthreads();
        {
            float xj[N];
            #pragma unroll
            for (int j=0;j<N;j++) xj[j] = bufL[j*STP + t];
            v4f X0 = {xj[0], xj[1], xj[2],  xj[3]};
            v4f X1 = {xj[4], xj[5], xj[6],  xj[7]};
            v4f X2 = {xj[8], xj[9], xj[10], xj[11]};
            float bias = gb[t];
            #pragma unroll
            for (int i=0;i<N;i++) {
                const v4f* ep = reinterpret_cast<const v4f*>(&pool[i*N]);
                v4f acc = __builtin_elementwise_fma(ep[0], X0,
                          __builtin_elementwise_fma(ep[1], X1, ep[2]*X2));
                float r = bias + ((acc.x + acc.y) + (acc.z + acc.w));
                if (useSkip) r = fmaf(ALPHA, skipv[i], r);
                xout[i*strideOut + t] = fmaxf(r, 0.f);
            }
        }
        __syncthreads();
    };

    // ---- MFMA stage (TW only): bufL/bufR <- xin @ {wl, wr} (bf16) ----
    auto stage_mfma = [&](const float* __restrict__ xin, int strideIn, int matL) {
        const int m = t & 15, quad = t >> 4;
        const int mc = (m < N) ? m : 0;        // clamp: rows 12..15 discarded anyway
        i4 aF[2];
        #pragma unroll
        for (int kt=0; kt<2; kt++) {
            const float* xp = &xin[mc*strideIn + kt*32 + quad*8];
            v4f lo = *reinterpret_cast<const v4f*>(xp);
            v4f hi = *reinterpret_cast<const v4f*>(xp + 4);
            unsigned u0 = __float_as_uint(lo.x) + 0x8000u, u1 = __float_as_uint(lo.y) + 0x8000u;
            unsigned u2 = __float_as_uint(lo.z) + 0x8000u, u3 = __float_as_uint(lo.w) + 0x8000u;
            unsigned u4 = __float_as_uint(hi.x) + 0x8000u, u5 = __float_as_uint(hi.y) + 0x8000u;
            unsigned u6 = __float_as_uint(hi.z) + 0x8000u, u7 = __float_as_uint(hi.w) + 0x8000u;
            i4 a;
            a.x = (int)__builtin_amdgcn_perm(u1, u0, 0x07060302u);
            a.y = (int)__builtin_amdgcn_perm(u3, u2, 0x07060302u);
            a.z = (int)__builtin_amdgcn_perm(u5, u4, 0x07060302u);
            a.w = (int)__builtin_amdgcn_perm(u7, u6, 0x07060302u);
            aF[kt] = a;
        }
        const i4* bbase = reinterpret_cast<const i4*>(wsT + 4096);
        #pragma unroll
        for (int mm=0; mm<2; mm++) {
            const i4* bp = bbase + (matL + mm)*512;
            v4f acc[4] = {z4, z4, z4, z4};
            #pragma unroll
            for (int nt=0; nt<4; nt++) {
                i4 b0 = bp[(0*4+nt)*64 + t];
                i4 b1 = bp[(1*4+nt)*64 + t];
                acc[nt] = __builtin_amdgcn_mfma_f32_16x16x32_bf16(as_v8s(aF[0]), as_v8s(b0), acc[nt], 0, 0, 0);
                acc[nt] = __builtin_amdgcn_mfma_f32_16x16x32_bf16(as_v8s(aF[1]), as_v8s(b1), acc[nt], 0, 0, 0);
            }
            float* dst = (mm == 0) ? bufL : bufR;
            if (quad < 3) {
                #pragma unroll
                for (int nt=0; nt<4; nt++) {
                    #pragma unroll
                    for (int r=0; r<4; r++)
                        dst[(quad*4+r)*STP + nt*16 + m] = acc[nt][r];
                }
            }
        }
    };

    // ---- fp32 VALU stage (fallback when TW=false) ----
    auto stage = [&](const float* __restrict__ xin, int strideIn,
                     const float* __restrict__ wl, const float* __restrict__ wr) {
        v2f al[N], ar[N];
        #pragma unroll
        for (int i=0;i<N;i++) { al[i] = z2; ar[i] = z2; }
        for (int c=0;c<HID;c+=4) {
            v2f wl01 = (v2f){wl[(c+0)*HID+t], wl[(c+1)*HID+t]};
            v2f wl23 = (v2f){wl[(c+2)*HID+t], wl[(c+3)*HID+t]};
            v2f wr01 = (v2f){wr[(c+0)*HID+t], wr[(c+1)*HID+t]};
            v2f wr23 = (v2f){wr[(c+2)*HID+t], wr[(c+3)*HID+t]};
            #pragma unroll
            for (int i=0;i<N;i++) {
                v4f xv = *reinterpret_cast<const v4f*>(&xin[i*strideIn + c]);
                al[i] = __builtin_elementwise_fma(xv.xy, wl01, al[i]);
                al[i] = __builtin_elementwise_fma(xv.zw, wl23, al[i]);
                ar[i] = __builtin_elementwise_fma(xv.xy, wr01, ar[i]);
                ar[i] = __builtin_elementwise_fma(xv.zw, wr23, ar[i]);
            }
        }
        #pragma unroll
        for (int i=0;i<N;i++) {
            bufL[i*STP + t] = al[i].x + al[i].y;
            bufR[i*STP + t] = ar[i].x + ar[i].y;
        }
    };

    // ---- GAT layer 1 (cin = 1; x0 = lat[:,2] from pool) ----
    {
        float wlv = g1_wl[t], wrv = g1_wr[t];
        #pragma unroll
        for (int i=0;i<N;i++) {
            float v = pool[i*3+2];
            bufL[i*STP + t] = v * wlv;
            bufR[i*STP + t] = v * wrv;
        }
    }
    gat_core(g1_att, g1_b, bufR, STP, 0);   // x1 -> bufR

    // ---- GAT layer 2 ----
    if (TW) stage_mfma(bufR, STP, 0); else stage(bufR, STP, g2_wl, g2_wr);
    gat_core(g2_att, g2_b, xB, HID, 0);     // x2 -> xB (persists)

    // ---- GAT layer 3 ----
    if (TW) stage_mfma(xB, HID, 2); else stage(xB, HID, g3_wl, g3_wr);
    gat_core(g3_att, g3_b, bufR, STP, 1);   // x3 -> bufR

    // ---- logits head: x3 @ lab_w + lab_b ----
    if (t < N*4) {
        int i = t >> 2, c = t & 3;
        float acc = lab_b[c];
        if (TW) {
            const float* lwT = wsT + 16384 + c*HID;
            #pragma unroll 4
            for (int h=0;h<HID;h+=4) {
                v4f xv = *reinterpret_cast<const v4f*>(&bufR[i*STP + h]);
                v4f w4 = *reinterpret_cast<const v4f*>(&lwT[h]);
                acc = fmaf(xv.x, w4.x, acc);
                acc = fmaf(xv.y, w4.y, acc);
                acc = fmaf(xv.z, w4.z, acc);
                acc = fmaf(xv.w, w4.w, acc);
            }
        } else {
            #pragma unroll 4
            for (int h=0;h<HID;h+=4) {
                v4f xv = *reinterpret_cast<const v4f*>(&bufR[i*STP + h]);
                acc = fmaf(xv.x, lab_w[(h+0)*4+c], acc);
                acc = fmaf(xv.y, lab_w[(h+1)*4+c], acc);
                acc = fmaf(xv.z, lab_w[(h+2)*4+c], acc);
                acc = fmaf(xv.w, lab_w[(h+3)*4+c], acc);
            }
        }
        out[OUT2 + (size_t)b*(N*4) + t] = acc;
    }

    // ---- GAT layer 4 ----
    if (TW) stage_mfma(xB, HID, 4); else stage(xB, HID, g4_wl, g4_wr);
    gat_core(g4_att, g4_b, bufR, STP, 1);   // x4 -> bufR

    // ---- values head ----
    if (t < N) {
        float acc = val_b[0];
        #pragma unroll 4
        for (int h=0;h<HID;h+=4) {
            v4f xv = *reinterpret_cast<const v4f*>(&bufR[t*STP + h]);
            v4f w4 = *reinterpret_cast<const v4f*>(&val_w[h]);
            acc = fmaf(xv.x, w4.x, acc);
            acc = fmaf(xv.y, w4.y, acc);
            acc = fmaf(xv.z, w4.z, acc);
            acc = fmaf(xv.w, w4.w, acc);
        }
        out[OUT3 + (size_t)b*N + t] = acc;
    }
}

extern "C" void kernel_launch(void* const* d_in, const int* in_sizes, int n_in,
                              void* d_out, int out_size, void* d_ws, size_t ws_size,
                              hipStream_t stream) {
    (void)in_sizes; (void)n_in; (void)out_size;
    const bool useT = (ws_size >= (16384 + 256)*sizeof(float));
    if (useT) {
        prep_kernel<<<dim3(113), dim3(64), 0, stream>>>(
            (const float*)d_in[3],
            (const float*)d_in[11], (const float*)d_in[12],
            (const float*)d_in[15], (const float*)d_in[16],
            (const float*)d_in[19], (const float*)d_in[20],
            (const float*)d_in[23],
            (float*)d_ws);
        gae_kernel<true><<<dim3(4096), dim3(64), 0, stream>>>(
            (const float*)d_in[0],
            (const float*)d_in[1],  (const float*)d_in[2],
            (const float*)d_in[3],  (const float*)d_in[4],
            (const float*)d_in[5],  (const float*)d_in[6],
            (const float*)d_in[7],  (const float*)d_in[8],  (const float*)d_in[9],  (const float*)d_in[10],
            (const float*)d_in[11], (const float*)d_in[12], (const float*)d_in[13], (const float*)d_in[14],
            (const float*)d_in[15], (const float*)d_in[16], (const float*)d_in[17], (const float*)d_in[18],
            (const float*)d_in[19], (const float*)d_in[20], (const float*)d_in[21], (const float*)d_in[22],
            (const float*)d_in[23], (const float*)d_in[24],
            (const float*)d_in[25], (const float*)d_in[26],
            (const float*)d_in[27], (const float*)d_in[28],
            (const float*)d_ws,
            (float*)d_out);
    } else {
        gae_kernel<false><<<dim3(4096), dim3(64), 0, stream>>>(
            (const float*)d_in[0],
            (const float*)d_in[1],  (const float*)d_in[2],
            (const float*)d_in[3],  (const float*)d_in[4],
            (const float*)d_in[5],  (const float*)d_in[6],
            (const float*)d_in[7],  (const float*)d_in[8],  (const float*)d_in[9],  (const float*)d_in[10],
            (const float*)d_in[11], (const float*)d_in[12], (const float*)d_in[13], (const float*)d_in[14],
            (const float*)d_in[15], (const float*)d_in[16], (const float*)d_in[17], (const float*)d_in[18],
            (const float*)d_in[19], (const float*)d_in[20], (const float*)d_in[21], (const float*)d_in[22],
            (const float*)d_in[23], (const float*)d_in[24],
            (const float*)d_in[25], (const float*)d_in[26],
            (const float*)d_in[27], (const float*)d_in[28],
            nullptr,
            (float*)d_out);
    }
}

// Round 4
// 153.261 us; speedup vs baseline: 1.3534x; 1.0384x over previous
//
#include <hip/hip_runtime.h>
#include <hip/hip_bf16.h>
#include <math.h>

#define N     12
#define HID   64
#define STP   68     // padded row stride for bufL/bufR (272 B rows, 16B-aligned)
#define SLOPE 0.2f
#define ALPHA 0.1f

typedef float v2f __attribute__((ext_vector_type(2)));
typedef float v4f __attribute__((ext_vector_type(4)));
typedef int   i4  __attribute__((ext_vector_type(4)));
typedef short v8s __attribute__((ext_vector_type(8)));

static __device__ __forceinline__ v8s as_v8s(i4 v) {
    union { i4 a; v8s b; } u; u.a = v; return u.b;
}

// flat output offsets (float32 elements)
#define OUT0 0          // batch[:,:,:4]
#define OUT1 196608     // batch[:,:,4:5]
#define OUT2 245760     // logits
#define OUT3 442368     // values
#define OUT4 491520     // latent

// ws layout (float offsets):
//   [0,4096)         enc_w2 transposed fp32
//   [4096,16384)     6 GAT matrices bf16 B-fragments
//   [16384,16640)    labT fp32
__global__ void prep_kernel(const float* __restrict__ enc_w2,
                            const float* __restrict__ g2_wl, const float* __restrict__ g2_wr,
                            const float* __restrict__ g3_wl, const float* __restrict__ g3_wr,
                            const float* __restrict__ g4_wl, const float* __restrict__ g4_wr,
                            const float* __restrict__ lab_w,
                            float* __restrict__ ws) {
    int t = threadIdx.x;
    int bx = blockIdx.x;
    if (bx < 64) {                       // enc_w2 fp32 transpose
        int c = bx;
        ws[t*64 + c] = enc_w2[c*64 + t];
        return;
    }
    if (bx == 112) {                     // labT
        #pragma unroll
        for (int c = 0; c < 4; c++) ws[16384 + c*64 + t] = lab_w[t*4 + c];
        return;
    }
    // B-fragment pack: 48 blocks = 6 matrices x 2 kt x 4 nt
    int idx = bx - 64;
    int mat = idx >> 3, rem = idx & 7;
    int kt = rem >> 2, nt = rem & 3;
    const float* src;
    switch (mat) {
        case 0: src = g2_wl; break;
        case 1: src = g2_wr; break;
        case 2: src = g3_wl; break;
        case 3: src = g3_wr; break;
        case 4: src = g4_wl; break;
        default: src = g4_wr; break;
    }
    int quad = t >> 4, col = t & 15;
    int n = nt*16 + col;
    unsigned* dst = (unsigned*)(ws + 4096) + mat*2048 + (kt*4+nt)*256 + t*4;
    #pragma unroll
    for (int jp = 0; jp < 4; jp++) {
        int k0 = kt*32 + quad*8 + 2*jp;
        __hip_bfloat16 h0 = __float2bfloat16(src[(k0+0)*64 + n]);
        __hip_bfloat16 h1 = __float2bfloat16(src[(k0+1)*64 + n]);
        unsigned u0 = *(unsigned short*)&h0, u1 = *(unsigned short*)&h1;
        dst[jp] = u0 | (u1 << 16);
    }
}

// R13: R0 structure, ZERO barriers. Blocks are single-wave (64 threads): LDS
// ops complete in order per wave and the compiler serializes dynamically-
// indexed LDS write->read with fine-grained lgkmcnt. Every __syncthreads()
// was costing a full vmcnt(0)+lgkmcnt(0) drain (~20 of them on the critical
// path) and blocked cross-phase prefetch of global loads (att vectors, MFMA
// B-frags, biases). Removing them lets the scheduler pipeline phases.
// + scoreAt: 2-accumulator h-split (halves the serial chain; +~12 VGPR).
// + aggregate xj/bias loads hoisted above softmax (in flight during stall).
// R3 lesson: NO aggressive unrolls (spill at 64-reg ceiling); keep loops
// rolled, pressure target <= ~100 VGPR.
template<bool TW>
__global__ __launch_bounds__(64, 3) void gae_kernel(
    const float* __restrict__ batch,
    const float* __restrict__ enc_w1, const float* __restrict__ enc_b1,
    const float* __restrict__ enc_w2, const float* __restrict__ enc_b2,
    const float* __restrict__ enc_w3, const float* __restrict__ enc_b3,
    const float* __restrict__ g1_wl, const float* __restrict__ g1_wr,
    const float* __restrict__ g1_att, const float* __restrict__ g1_b,
    const float* __restrict__ g2_wl, const float* __restrict__ g2_wr,
    const float* __restrict__ g2_att, const float* __restrict__ g2_b,
    const float* __restrict__ g3_wl, const float* __restrict__ g3_wr,
    const float* __restrict__ g3_att, const float* __restrict__ g3_b,
    const float* __restrict__ g4_wl, const float* __restrict__ g4_wr,
    const float* __restrict__ g4_att, const float* __restrict__ g4_b,
    const float* __restrict__ lab_w, const float* __restrict__ lab_b,
    const float* __restrict__ val_w, const float* __restrict__ val_b,
    const float* __restrict__ skip_w, const float* __restrict__ skip_b,
    const float* __restrict__ wsT,
    float* __restrict__ out)
{
    const int b = blockIdx.x;
    const int t = threadIdx.x;

    __shared__ __align__(16) float lds[2560];
    float* bufL = lds;                         // stride STP
    float* bufR = lds + N*STP;                 // stride STP
    float* xB   = lds + 2*N*STP;               // stride HID (broadcast-read only)
    float* pool = lds + 2*N*STP + N*HID;       // batch(60)->lat(36)->e(144)
    unsigned char* pairs8 = (unsigned char*)&lds[2544];  // 64 B compacted pair list

    const v2f z2 = {0.f, 0.f};
    const v4f z4 = {0.f, 0.f, 0.f, 0.f};
    const v4f s4 = {SLOPE, SLOPE, SLOPE, SLOPE};

    // score-pair decomposition (144 pairs, 3 slots of 64/64/16)
    const int p0 = t,        i0 = p0 / N, j0 = p0 - i0*N;
    const int p1 = t + 64,   i1 = p1 / N, j1 = p1 - i1*N;
    const int p2 = (t < 16) ? (t + 128) : 143;
    const int i2 = p2 / N,   j2 = p2 - i2*N;

    // ---- stage batch into pool, emit passthrough outputs 0/1 ----
    if (t < N*5) {
        float v = batch[b*(N*5) + t];
        pool[t] = v;
        int i = t / 5, f = t - i*5;
        if (f < 4) out[OUT0 + (size_t)b*(N*4) + i*4 + f] = v;
        else       out[OUT1 + (size_t)b*N + i] = v;
    }

    // ---- encoder layer 1 ----
    {
        float acc[N];
        float bias = enc_b1[t];
        #pragma unroll
        for (int i=0;i<N;i++) acc[i] = bias;
        #pragma unroll
        for (int f=0; f<5; f++) {
            float w = enc_w1[f*HID + t];
            #pragma unroll
            for (int i=0;i<N;i++) acc[i] = fmaf(pool[i*5+f], w, acc[i]);
        }
        #pragma unroll
        for (int i=0;i<N;i++) bufL[i*STP + t] = fmaxf(acc[i], 0.f);
    }

    // ---- encoder layer 2 (fp32; K-loop ROLLED, 12 independent acc chains) ----
    {
        v2f acc[N];
        #pragma unroll
        for (int i=0;i<N;i++) acc[i] = z2;
        const float* w2p = TW ? (wsT + t*HID) : nullptr;
        for (int c=0;c<HID;c+=4) {
            v2f w01, w23;
            if (TW) {
                v4f w4 = *reinterpret_cast<const v4f*>(&w2p[c]);
                w01 = w4.xy; w23 = w4.zw;
            } else {
                w01 = (v2f){enc_w2[(c+0)*HID+t], enc_w2[(c+1)*HID+t]};
                w23 = (v2f){enc_w2[(c+2)*HID+t], enc_w2[(c+3)*HID+t]};
            }
            #pragma unroll
            for (int i=0;i<N;i++) {
                v4f xv = *reinterpret_cast<const v4f*>(&bufL[i*STP + c]);
                acc[i] = __builtin_elementwise_fma(xv.xy, w01, acc[i]);
                acc[i] = __builtin_elementwise_fma(xv.zw, w23, acc[i]);
            }
        }
        float bias = enc_b2[t];
        #pragma unroll
        for (int i=0;i<N;i++) bufR[i*STP + t] = fmaxf(bias + acc[i].x + acc[i].y, 0.f);
    }

    // ---- latent = h2 @ W3 + b3 (lanes 0..35) -> pool[0..35] ----
    if (t < N*3) {
        int i = t / 3, c = t - i*3;
        float acc = enc_b3[c];
        for (int k=0;k<HID;k+=4) {
            v4f xv = *reinterpret_cast<const v4f*>(&bufR[i*STP + k]);
            acc = fmaf(xv.x, enc_w3[(k+0)*3+c], acc);
            acc = fmaf(xv.y, enc_w3[(k+1)*3+c], acc);
            acc = fmaf(xv.z, enc_w3[(k+2)*3+c], acc);
            acc = fmaf(xv.w, enc_w3[(k+3)*3+c], acc);
        }
        pool[t] = acc;
        out[OUT4 + (size_t)b*(N*3) + t] = acc;
    }

    // ---- skip connection -> registers ----
    float skipv[N];
    {
        float w0 = skip_w[t], w1 = skip_w[HID+t], w2 = skip_w[2*HID+t];
        float bias = skip_b[t];
        #pragma unroll
        for (int i=0;i<N;i++) {
            float v = bias;
            v = fmaf(pool[i*3+0], w0, v);
            v = fmaf(pool[i*3+1], w1, v);
            v = fmaf(pool[i*3+2], w2, v);
            skipv[i] = v;
        }
    }

    // ---- Gabriel adjacency via ballots ----
    auto gab = [&](int i, int j)->bool {
        if (i == j) return false;
        float pix = pool[i*3], piy = pool[i*3+1];
        float pjx = pool[j*3], pjy = pool[j*3+1];
        float mx = (pix + pjx) * 0.5f, my = (piy + pjy) * 0.5f;
        float dx = pix - pjx, dy = piy - pjy;
        float r2 = (dx*dx + dy*dy) * 0.25f;
        bool g = true;
        #pragma unroll
        for (int k=0;k<N;k++) {
            float ex = pool[k*3] - mx, ey = pool[k*3+1] - my;
            bool ok = (k == i) || (k == j) || (ex*ex + ey*ey > r2);
            g = g && ok;
        }
        return g;
    };
    unsigned long long gb0 = __ballot(gab(i0, j0));
    unsigned long long gb1 = __ballot(gab(i1, j1));
    unsigned long long gb2 = __ballot((t < 16) && gab(i2, j2));
    auto gbit = [&](int p)->int {
        unsigned long long m = (p < 64) ? gb0 : ((p < 128) ? gb1 : gb2);
        return (int)((m >> (p & 63)) & 1ull);
    };
    const int adjA = gbit(p0) | gbit(j0*N+i0) | (i0 == j0);
    const int adjB = gbit(p1) | gbit(j1*N+i1) | (i1 == j1);
    const int adjC = (t < 16) ? (gbit(p2) | gbit(j2*N+i2) | (i2 == j2)) : 0;

    // ---- compact valid pairs ----
    auto mbcnt64 = [&](unsigned long long m)->int {
        return __builtin_amdgcn_mbcnt_hi((unsigned)(m >> 32),
               __builtin_amdgcn_mbcnt_lo((unsigned)m, 0));
    };
    const unsigned long long am0 = __ballot(adjA != 0);
    const unsigned long long am1 = __ballot(adjB != 0);
    const unsigned long long am2 = __ballot(adjC != 0);
    const int c0  = __popcll(am0);
    const int c01 = c0 + __popcll(am1);
    const int nv  = c01 + __popcll(am2);
    const int idx0 = mbcnt64(am0);
    const int idx1 = c0  + mbcnt64(am1);
    const int idx2 = c01 + mbcnt64(am2);
    if (adjA)               pairs8[idx0] = (unsigned char)p0;
    if (adjB && idx1 < 64)  pairs8[idx1] = (unsigned char)p1;
    if (adjC && idx2 < 64)  pairs8[idx2] = (unsigned char)p2;
    const bool ovB = adjB && (idx1 >= 64);
    const bool ovC = adjC && (idx2 >= 64);
    const int nvc = nv < 64 ? nv : 64;

    // ---- score for one adjacent pair: 2-accumulator h-split (halved chain) ----
    auto scoreAt = [&](int i, int j, const float* __restrict__ att)->float {
        const float* Lj = &bufL[j*STP];
        const float* Ri = &bufR[i*STP];
        v4f a0 = z4, a1 = z4;
        for (int h=0; h<HID; h+=8) {
            v4f t0 = *reinterpret_cast<const v4f*>(&att[h]);
            v4f t1 = *reinterpret_cast<const v4f*>(&att[h+4]);
            v4f xl0 = *reinterpret_cast<const v4f*>(Lj + h);
            v4f xl1 = *reinterpret_cast<const v4f*>(Lj + h + 4);
            v4f xr0 = *reinterpret_cast<const v4f*>(Ri + h);
            v4f xr1 = *reinterpret_cast<const v4f*>(Ri + h + 4);
            v4f s0 = xl0 + xr0;
            v4f s1 = xl1 + xr1;
            v4f l0 = __builtin_elementwise_fma(s4, __builtin_elementwise_min(s0, z4),
                                               __builtin_elementwise_max(s0, z4));
            v4f l1 = __builtin_elementwise_fma(s4, __builtin_elementwise_min(s1, z4),
                                               __builtin_elementwise_max(s1, z4));
            a0 = __builtin_elementwise_fma(t0, l0, a0);
            a1 = __builtin_elementwise_fma(t1, l1, a1);
        }
        v4f a = a0 + a1;
        return (a.x + a.y) + (a.z + a.w);
    };

    // ---- GATv2 core: sparse score -> softmax -> aggregate (NO barriers) ----
    auto gat_core = [&](const float* __restrict__ att, const float* __restrict__ gb,
                        float* __restrict__ xout, int strideOut, int useSkip) {
        pool[t] = -1e9f; pool[t+64] = -1e9f;
        if (t < 16) pool[t+128] = -1e9f;
        if (t < nvc) {
            int p = pairs8[t];
            int i = (p * 171) >> 11;           // p/12 for p<144
            int j = p - i*N;
            pool[p] = scoreAt(i, j, att);
        }
        if (nv > 64) {
            if (ovB) pool[p1] = scoreAt(i1, j1, att);
            if (ovC) pool[p2] = scoreAt(i2, j2, att);
        }
        // hoisted: xj/bias depend only on bufL/gb -> in flight during softmax
        float xj[N];
        #pragma unroll
        for (int j=0;j<N;j++) xj[j] = bufL[j*STP + t];
        float bias = gb[t];
        if (t < N) {   // row softmax
            float m = -2e9f;
            #pragma unroll
            for (int j=0;j<N;j++) m = fmaxf(m, pool[t*N+j]);
            float tmp[N]; float sum = 0.f;
            #pragma unroll
            for (int j=0;j<N;j++) { float v = __expf(pool[t*N+j] - m); tmp[j] = v; sum += v; }
            float inv = 1.0f / sum;
            #pragma unroll
            for (int j=0;j<N;j++) pool[t*N+j] = tmp[j] * inv;
        }
        {
            v4f X0 = {xj[0], xj[1], xj[2],  xj[3]};
            v4f X1 = {xj[4], xj[5], xj[6],  xj[7]};
            v4f X2 = {xj[8], xj[9], xj[10], xj[11]};
            #pragma unroll
            for (int i=0;i<N;i++) {
                const v4f* ep = reinterpret_cast<const v4f*>(&pool[i*N]);
                v4f acc = __builtin_elementwise_fma(ep[0], X0,
                          __builtin_elementwise_fma(ep[1], X1, ep[2]*X2));
                float r = bias + ((acc.x + acc.y) + (acc.z + acc.w));
                if (useSkip) r = fmaf(ALPHA, skipv[i], r);
                xout[i*strideOut + t] = fmaxf(r, 0.f);
            }
        }
    };

    // ---- MFMA stage (TW only): bufL/bufR <- xin @ {wl, wr} (bf16) ----
    auto stage_mfma = [&](const float* __restrict__ xin, int strideIn, int matL) {
        const int m = t & 15, quad = t >> 4;
        const int mc = (m < N) ? m : 0;        // clamp: rows 12..15 discarded anyway
        i4 aF[2];
        #pragma unroll
        for (int kt=0; kt<2; kt++) {
            const float* xp = &xin[mc*strideIn + kt*32 + quad*8];
            v4f lo = *reinterpret_cast<const v4f*>(xp);
            v4f hi = *reinterpret_cast<const v4f*>(xp + 4);
            unsigned u0 = __float_as_uint(lo.x) + 0x8000u, u1 = __float_as_uint(lo.y) + 0x8000u;
            unsigned u2 = __float_as_uint(lo.z) + 0x8000u, u3 = __float_as_uint(lo.w) + 0x8000u;
            unsigned u4 = __float_as_uint(hi.x) + 0x8000u, u5 = __float_as_uint(hi.y) + 0x8000u;
            unsigned u6 = __float_as_uint(hi.z) + 0x8000u, u7 = __float_as_uint(hi.w) + 0x8000u;
            i4 a;
            a.x = (int)__builtin_amdgcn_perm(u1, u0, 0x07060302u);
            a.y = (int)__builtin_amdgcn_perm(u3, u2, 0x07060302u);
            a.z = (int)__builtin_amdgcn_perm(u5, u4, 0x07060302u);
            a.w = (int)__builtin_amdgcn_perm(u7, u6, 0x07060302u);
            aF[kt] = a;
        }
        const i4* bbase = reinterpret_cast<const i4*>(wsT + 4096);
        #pragma unroll
        for (int mm=0; mm<2; mm++) {
            const i4* bp = bbase + (matL + mm)*512;
            v4f acc[4] = {z4, z4, z4, z4};
            #pragma unroll
            for (int nt=0; nt<4; nt++) {
                i4 b0 = bp[(0*4+nt)*64 + t];
                i4 b1 = bp[(1*4+nt)*64 + t];
                acc[nt] = __builtin_amdgcn_mfma_f32_16x16x32_bf16(as_v8s(aF[0]), as_v8s(b0), acc[nt], 0, 0, 0);
                acc[nt] = __builtin_amdgcn_mfma_f32_16x16x32_bf16(as_v8s(aF[1]), as_v8s(b1), acc[nt], 0, 0, 0);
            }
            float* dst = (mm == 0) ? bufL : bufR;
            if (quad < 3) {
                #pragma unroll
                for (int nt=0; nt<4; nt++) {
                    #pragma unroll
                    for (int r=0; r<4; r++)
                        dst[(quad*4+r)*STP + nt*16 + m] = acc[nt][r];
                }
            }
        }
    };

    // ---- fp32 VALU stage (fallback when TW=false) ----
    auto stage = [&](const float* __restrict__ xin, int strideIn,
                     const float* __restrict__ wl, const float* __restrict__ wr) {
        v2f al[N], ar[N];
        #pragma unroll
        for (int i=0;i<N;i++) { al[i] = z2; ar[i] = z2; }
        for (int c=0;c<HID;c+=4) {
            v2f wl01 = (v2f){wl[(c+0)*HID+t], wl[(c+1)*HID+t]};
            v2f wl23 = (v2f){wl[(c+2)*HID+t], wl[(c+3)*HID+t]};
            v2f wr01 = (v2f){wr[(c+0)*HID+t], wr[(c+1)*HID+t]};
            v2f wr23 = (v2f){wr[(c+2)*HID+t], wr[(c+3)*HID+t]};
            #pragma unroll
            for (int i=0;i<N;i++) {
                v4f xv = *reinterpret_cast<const v4f*>(&xin[i*strideIn + c]);
                al[i] = __builtin_elementwise_fma(xv.xy, wl01, al[i]);
                al[i] = __builtin_elementwise_fma(xv.zw, wl23, al[i]);
                ar[i] = __builtin_elementwise_fma(xv.xy, wr01, ar[i]);
                ar[i] = __builtin_elementwise_fma(xv.zw, wr23, ar[i]);
            }
        }
        #pragma unroll
        for (int i=0;i<N;i++) {
            bufL[i*STP + t] = al[i].x + al[i].y;
            bufR[i*STP + t] = ar[i].x + ar[i].y;
        }
    };

    // ---- GAT layer 1 (cin = 1; x0 = lat[:,2] from pool) ----
    {
        float wlv = g1_wl[t], wrv = g1_wr[t];
        #pragma unroll
        for (int i=0;i<N;i++) {
            float v = pool[i*3+2];
            bufL[i*STP + t] = v * wlv;
            bufR[i*STP + t] = v * wrv;
        }
    }
    gat_core(g1_att, g1_b, bufR, STP, 0);   // x1 -> bufR

    // ---- GAT layer 2 ----
    if (TW) stage_mfma(bufR, STP, 0); else stage(bufR, STP, g2_wl, g2_wr);
    gat_core(g2_att, g2_b, xB, HID, 0);     // x2 -> xB (persists)

    // ---- GAT layer 3 ----
    if (TW) stage_mfma(xB, HID, 2); else stage(xB, HID, g3_wl, g3_wr);
    gat_core(g3_att, g3_b, bufR, STP, 1);   // x3 -> bufR

    // ---- logits head: x3 @ lab_w + lab_b ----
    if (t < N*4) {
        int i = t >> 2, c = t & 3;
        float acc = lab_b[c];
        if (TW) {
            const float* lwT = wsT + 16384 + c*HID;
            for (int h=0;h<HID;h+=4) {
                v4f xv = *reinterpret_cast<const v4f*>(&bufR[i*STP + h]);
                v4f w4 = *reinterpret_cast<const v4f*>(&lwT[h]);
                acc = fmaf(xv.x, w4.x, acc);
                acc = fmaf(xv.y, w4.y, acc);
                acc = fmaf(xv.z, w4.z, acc);
                acc = fmaf(xv.w, w4.w, acc);
            }
        } else {
            for (int h=0;h<HID;h+=4) {
                v4f xv = *reinterpret_cast<const v4f*>(&bufR[i*STP + h]);
                acc = fmaf(xv.x, lab_w[(h+0)*4+c], acc);
                acc = fmaf(xv.y, lab_w[(h+1)*4+c], acc);
                acc = fmaf(xv.z, lab_w[(h+2)*4+c], acc);
                acc = fmaf(xv.w, lab_w[(h+3)*4+c], acc);
            }
        }
        out[OUT2 + (size_t)b*(N*4) + t] = acc;
    }

    // ---- GAT layer 4 ----
    if (TW) stage_mfma(xB, HID, 4); else stage(xB, HID, g4_wl, g4_wr);
    gat_core(g4_att, g4_b, bufR, STP, 1);   // x4 -> bufR

    // ---- values head ----
    if (t < N) {
        float acc = val_b[0];
        for (int h=0;h<HID;h+=4) {
            v4f xv = *reinterpret_cast<const v4f*>(&bufR[t*STP + h]);
            v4f w4 = *reinterpret_cast<const v4f*>(&val_w[h]);
            acc = fmaf(xv.x, w4.x, acc);
            acc = fmaf(xv.y, w4.y, acc);
            acc = fmaf(xv.z, w4.z, acc);
            acc = fmaf(xv.w, w4.w, acc);
        }
        out[OUT3 + (size_t)b*N + t] = acc;
    }
}

extern "C" void kernel_launch(void* const* d_in, const int* in_sizes, int n_in,
                              void* d_out, int out_size, void* d_ws, size_t ws_size,
                              hipStream_t stream) {
    (void)in_sizes; (void)n_in; (void)out_size;
    const bool useT = (ws_size >= (16384 + 256)*sizeof(float));
    if (useT) {
        prep_kernel<<<dim3(113), dim3(64), 0, stream>>>(
            (const float*)d_in[3],
            (const float*)d_in[11], (const float*)d_in[12],
            (const float*)d_in[15], (const float*)d_in[16],
            (const float*)d_in[19], (const float*)d_in[20],
            (const float*)d_in[23],
            (float*)d_ws);
        gae_kernel<true><<<dim3(4096), dim3(64), 0, stream>>>(
            (const float*)d_in[0],
            (const float*)d_in[1],  (const float*)d_in[2],
            (const float*)d_in[3],  (const float*)d_in[4],
            (const float*)d_in[5],  (const float*)d_in[6],
            (const float*)d_in[7],  (const float*)d_in[8],  (const float*)d_in[9],  (const float*)d_in[10],
            (const float*)d_in[11], (const float*)d_in[12], (const float*)d_in[13], (const float*)d_in[14],
            (const float*)d_in[15], (const float*)d_in[16], (const float*)d_in[17], (const float*)d_in[18],
            (const float*)d_in[19], (const float*)d_in[20], (const float*)d_in[21], (const float*)d_in[22],
            (const float*)d_in[23], (const float*)d_in[24],
            (const float*)d_in[25], (const float*)d_in[26],
            (const float*)d_in[27], (const float*)d_in[28],
            (const float*)d_ws,
            (float*)d_out);
    } else {
        gae_kernel<false><<<dim3(4096), dim3(64), 0, stream>>>(
            (const float*)d_in[0],
            (const float*)d_in[1],  (const float*)d_in[2],
            (const float*)d_in[3],  (const float*)d_in[4],
            (const float*)d_in[5],  (const float*)d_in[6],
            (const float*)d_in[7],  (const float*)d_in[8],  (const float*)d_in[9],  (const float*)d_in[10],
            (const float*)d_in[11], (const float*)d_in[12], (const float*)d_in[13], (const float*)d_in[14],
            (const float*)d_in[15], (const float*)d_in[16], (const float*)d_in[17], (const float*)d_in[18],
            (const float*)d_in[19], (const float*)d_in[20], (const float*)d_in[21], (const float*)d_in[22],
            (const float*)d_in[23], (const float*)d_in[24],
            (const float*)d_in[25], (const float*)d_in[26],
            (const float*)d_in[27], (const float*)d_in[28],
            nullptr,
            (float*)d_out);
    }
}

// Round 5
// 149.833 us; speedup vs baseline: 1.3844x; 1.0229x over previous
//
#include <hip/hip_runtime.h>
#include <hip/hip_bf16.h>
#include <math.h>

#define N     12
#define HID   64
#define STP   68     // padded row stride for bufL/bufR (272 B rows, 16B-aligned)
#define SLOPE 0.2f
#define ALPHA 0.1f

typedef float v2f __attribute__((ext_vector_type(2)));
typedef float v4f __attribute__((ext_vector_type(4)));
typedef int   i4  __attribute__((ext_vector_type(4)));
typedef short v8s __attribute__((ext_vector_type(8)));

static __device__ __forceinline__ v8s as_v8s(i4 v) {
    union { i4 a; v8s b; } u; u.a = v; return u.b;
}

// flat output offsets (float32 elements)
#define OUT0 0          // batch[:,:,:4]
#define OUT1 196608     // batch[:,:,4:5]
#define OUT2 245760     // logits
#define OUT3 442368     // values
#define OUT4 491520     // latent

// ws layout (float offsets):
//   [0,4096)         enc_w2 transposed fp32
//   [4096,16384)     6 GAT matrices bf16 B-fragments
//   [16384,16640)    labT fp32
__global__ void prep_kernel(const float* __restrict__ enc_w2,
                            const float* __restrict__ g2_wl, const float* __restrict__ g2_wr,
                            const float* __restrict__ g3_wl, const float* __restrict__ g3_wr,
                            const float* __restrict__ g4_wl, const float* __restrict__ g4_wr,
                            const float* __restrict__ lab_w,
                            float* __restrict__ ws) {
    int t = threadIdx.x;
    int bx = blockIdx.x;
    if (bx < 64) {                       // enc_w2 fp32 transpose
        int c = bx;
        ws[t*64 + c] = enc_w2[c*64 + t];
        return;
    }
    if (bx == 112) {                     // labT
        #pragma unroll
        for (int c = 0; c < 4; c++) ws[16384 + c*64 + t] = lab_w[t*4 + c];
        return;
    }
    // B-fragment pack: 48 blocks = 6 matrices x 2 kt x 4 nt
    int idx = bx - 64;
    int mat = idx >> 3, rem = idx & 7;
    int kt = rem >> 2, nt = rem & 3;
    const float* src;
    switch (mat) {
        case 0: src = g2_wl; break;
        case 1: src = g2_wr; break;
        case 2: src = g3_wl; break;
        case 3: src = g3_wr; break;
        case 4: src = g4_wl; break;
        default: src = g4_wr; break;
    }
    int quad = t >> 4, col = t & 15;
    int n = nt*16 + col;
    unsigned* dst = (unsigned*)(ws + 4096) + mat*2048 + (kt*4+nt)*256 + t*4;
    #pragma unroll
    for (int jp = 0; jp < 4; jp++) {
        int k0 = kt*32 + quad*8 + 2*jp;
        __hip_bfloat16 h0 = __float2bfloat16(src[(k0+0)*64 + n]);
        __hip_bfloat16 h1 = __float2bfloat16(src[(k0+1)*64 + n]);
        unsigned u0 = *(unsigned short*)&h0, u1 = *(unsigned short*)&h1;
        dst[jp] = u0 | (u1 << 16);
    }
}

// R14: R13 (barrier-free 1-wave) + VALU diet on the two biggest blocks.
// R13 post-mortem: ~6.5k wave-VALU inst/graph, score = 44% of it.
// 1. lrelu(s) = max(s, SLOPE*s)  (2 ops vs min/max/fma 3) -> score 5->4
//    ops/elem, -512 VALU/graph.
// 2. softmax: keep E UNNORMALIZED; fold 1/sum into aggregate (dot*inv_i).
//    Row max/sum via ds_read_b128 + vector reduce; exp goes wave-parallel
//    over all 144 entries (rowmax broadcast via ds_bpermute); inv via shfl.
//    Removes the 12-lane serial exp chain + 12 LDS writes per layer.
// Keep: fp32 enc path (adjacency exactness), rolled K-loops (R3: unroll
// spills at 64-reg ceiling), no barriers (single wave).
template<bool TW>
__global__ __launch_bounds__(64, 3) void gae_kernel(
    const float* __restrict__ batch,
    const float* __restrict__ enc_w1, const float* __restrict__ enc_b1,
    const float* __restrict__ enc_w2, const float* __restrict__ enc_b2,
    const float* __restrict__ enc_w3, const float* __restrict__ enc_b3,
    const float* __restrict__ g1_wl, const float* __restrict__ g1_wr,
    const float* __restrict__ g1_att, const float* __restrict__ g1_b,
    const float* __restrict__ g2_wl, const float* __restrict__ g2_wr,
    const float* __restrict__ g2_att, const float* __restrict__ g2_b,
    const float* __restrict__ g3_wl, const float* __restrict__ g3_wr,
    const float* __restrict__ g3_att, const float* __restrict__ g3_b,
    const float* __restrict__ g4_wl, const float* __restrict__ g4_wr,
    const float* __restrict__ g4_att, const float* __restrict__ g4_b,
    const float* __restrict__ lab_w, const float* __restrict__ lab_b,
    const float* __restrict__ val_w, const float* __restrict__ val_b,
    const float* __restrict__ skip_w, const float* __restrict__ skip_b,
    const float* __restrict__ wsT,
    float* __restrict__ out)
{
    const int b = blockIdx.x;
    const int t = threadIdx.x;

    __shared__ __align__(16) float lds[2560];
    float* bufL = lds;                         // stride STP
    float* bufR = lds + N*STP;                 // stride STP
    float* xB   = lds + 2*N*STP;               // stride HID (broadcast-read only)
    float* pool = lds + 2*N*STP + N*HID;       // batch(60)->lat(36)->e(144)
    unsigned char* pairs8 = (unsigned char*)&lds[2544];  // 64 B compacted pair list

    const v2f z2 = {0.f, 0.f};
    const v4f z4 = {0.f, 0.f, 0.f, 0.f};
    const v4f s4 = {SLOPE, SLOPE, SLOPE, SLOPE};

    // score-pair decomposition (144 pairs, 3 slots of 64/64/16)
    const int p0 = t,        i0 = p0 / N, j0 = p0 - i0*N;
    const int p1 = t + 64,   i1 = p1 / N, j1 = p1 - i1*N;
    const int p2 = (t < 16) ? (t + 128) : 143;
    const int i2 = p2 / N,   j2 = p2 - i2*N;

    // ---- stage batch into pool, emit passthrough outputs 0/1 ----
    if (t < N*5) {
        float v = batch[b*(N*5) + t];
        pool[t] = v;
        int i = t / 5, f = t - i*5;
        if (f < 4) out[OUT0 + (size_t)b*(N*4) + i*4 + f] = v;
        else       out[OUT1 + (size_t)b*N + i] = v;
    }

    // ---- encoder layer 1 ----
    {
        float acc[N];
        float bias = enc_b1[t];
        #pragma unroll
        for (int i=0;i<N;i++) acc[i] = bias;
        #pragma unroll
        for (int f=0; f<5; f++) {
            float w = enc_w1[f*HID + t];
            #pragma unroll
            for (int i=0;i<N;i++) acc[i] = fmaf(pool[i*5+f], w, acc[i]);
        }
        #pragma unroll
        for (int i=0;i<N;i++) bufL[i*STP + t] = fmaxf(acc[i], 0.f);
    }

    // ---- encoder layer 2 (fp32; K-loop ROLLED, 12 independent acc chains) ----
    {
        v2f acc[N];
        #pragma unroll
        for (int i=0;i<N;i++) acc[i] = z2;
        const float* w2p = TW ? (wsT + t*HID) : nullptr;
        for (int c=0;c<HID;c+=4) {
            v2f w01, w23;
            if (TW) {
                v4f w4 = *reinterpret_cast<const v4f*>(&w2p[c]);
                w01 = w4.xy; w23 = w4.zw;
            } else {
                w01 = (v2f){enc_w2[(c+0)*HID+t], enc_w2[(c+1)*HID+t]};
                w23 = (v2f){enc_w2[(c+2)*HID+t], enc_w2[(c+3)*HID+t]};
            }
            #pragma unroll
            for (int i=0;i<N;i++) {
                v4f xv = *reinterpret_cast<const v4f*>(&bufL[i*STP + c]);
                acc[i] = __builtin_elementwise_fma(xv.xy, w01, acc[i]);
                acc[i] = __builtin_elementwise_fma(xv.zw, w23, acc[i]);
            }
        }
        float bias = enc_b2[t];
        #pragma unroll
        for (int i=0;i<N;i++) bufR[i*STP + t] = fmaxf(bias + acc[i].x + acc[i].y, 0.f);
    }

    // ---- latent = h2 @ W3 + b3 (lanes 0..35) -> pool[0..35] ----
    if (t < N*3) {
        int i = t / 3, c = t - i*3;
        float acc = enc_b3[c];
        for (int k=0;k<HID;k+=4) {
            v4f xv = *reinterpret_cast<const v4f*>(&bufR[i*STP + k]);
            acc = fmaf(xv.x, enc_w3[(k+0)*3+c], acc);
            acc = fmaf(xv.y, enc_w3[(k+1)*3+c], acc);
            acc = fmaf(xv.z, enc_w3[(k+2)*3+c], acc);
            acc = fmaf(xv.w, enc_w3[(k+3)*3+c], acc);
        }
        pool[t] = acc;
        out[OUT4 + (size_t)b*(N*3) + t] = acc;
    }

    // ---- skip connection -> registers ----
    float skipv[N];
    {
        float w0 = skip_w[t], w1 = skip_w[HID+t], w2 = skip_w[2*HID+t];
        float bias = skip_b[t];
        #pragma unroll
        for (int i=0;i<N;i++) {
            float v = bias;
            v = fmaf(pool[i*3+0], w0, v);
            v = fmaf(pool[i*3+1], w1, v);
            v = fmaf(pool[i*3+2], w2, v);
            skipv[i] = v;
        }
    }

    // ---- Gabriel adjacency via ballots ----
    auto gab = [&](int i, int j)->bool {
        if (i == j) return false;
        float pix = pool[i*3], piy = pool[i*3+1];
        float pjx = pool[j*3], pjy = pool[j*3+1];
        float mx = (pix + pjx) * 0.5f, my = (piy + pjy) * 0.5f;
        float dx = pix - pjx, dy = piy - pjy;
        float r2 = (dx*dx + dy*dy) * 0.25f;
        bool g = true;
        #pragma unroll
        for (int k=0;k<N;k++) {
            float ex = pool[k*3] - mx, ey = pool[k*3+1] - my;
            bool ok = (k == i) || (k == j) || (ex*ex + ey*ey > r2);
            g = g && ok;
        }
        return g;
    };
    unsigned long long gb0 = __ballot(gab(i0, j0));
    unsigned long long gb1 = __ballot(gab(i1, j1));
    unsigned long long gb2 = __ballot((t < 16) && gab(i2, j2));
    auto gbit = [&](int p)->int {
        unsigned long long m = (p < 64) ? gb0 : ((p < 128) ? gb1 : gb2);
        return (int)((m >> (p & 63)) & 1ull);
    };
    const int adjA = gbit(p0) | gbit(j0*N+i0) | (i0 == j0);
    const int adjB = gbit(p1) | gbit(j1*N+i1) | (i1 == j1);
    const int adjC = (t < 16) ? (gbit(p2) | gbit(j2*N+i2) | (i2 == j2)) : 0;

    // ---- compact valid pairs ----
    auto mbcnt64 = [&](unsigned long long m)->int {
        return __builtin_amdgcn_mbcnt_hi((unsigned)(m >> 32),
               __builtin_amdgcn_mbcnt_lo((unsigned)m, 0));
    };
    const unsigned long long am0 = __ballot(adjA != 0);
    const unsigned long long am1 = __ballot(adjB != 0);
    const unsigned long long am2 = __ballot(adjC != 0);
    const int c0  = __popcll(am0);
    const int c01 = c0 + __popcll(am1);
    const int nv  = c01 + __popcll(am2);
    const int idx0 = mbcnt64(am0);
    const int idx1 = c0  + mbcnt64(am1);
    const int idx2 = c01 + mbcnt64(am2);
    if (adjA)               pairs8[idx0] = (unsigned char)p0;
    if (adjB && idx1 < 64)  pairs8[idx1] = (unsigned char)p1;
    if (adjC && idx2 < 64)  pairs8[idx2] = (unsigned char)p2;
    const bool ovB = adjB && (idx1 >= 64);
    const bool ovC = adjC && (idx2 >= 64);
    const int nvc = nv < 64 ? nv : 64;

    // ---- score: 2-acc h-split; lrelu(s) = max(s, SLOPE*s) (4 ops/elem) ----
    auto scoreAt = [&](int i, int j, const float* __restrict__ att)->float {
        const float* Lj = &bufL[j*STP];
        const float* Ri = &bufR[i*STP];
        v4f a0 = z4, a1 = z4;
        for (int h=0; h<HID; h+=8) {
            v4f t0 = *reinterpret_cast<const v4f*>(&att[h]);
            v4f t1 = *reinterpret_cast<const v4f*>(&att[h+4]);
            v4f xl0 = *reinterpret_cast<const v4f*>(Lj + h);
            v4f xl1 = *reinterpret_cast<const v4f*>(Lj + h + 4);
            v4f xr0 = *reinterpret_cast<const v4f*>(Ri + h);
            v4f xr1 = *reinterpret_cast<const v4f*>(Ri + h + 4);
            v4f s0 = xl0 + xr0;
            v4f s1 = xl1 + xr1;
            v4f l0 = __builtin_elementwise_max(s0, s0 * s4);
            v4f l1 = __builtin_elementwise_max(s1, s1 * s4);
            a0 = __builtin_elementwise_fma(t0, l0, a0);
            a1 = __builtin_elementwise_fma(t1, l1, a1);
        }
        v4f a = a0 + a1;
        return (a.x + a.y) + (a.z + a.w);
    };

    auto bper = [&](float v, int lane)->float {
        return __int_as_float(__builtin_amdgcn_ds_bpermute(lane << 2, __float_as_int(v)));
    };

    // ---- GATv2 core: sparse score -> unnormalized softmax -> aggregate*inv ----
    auto gat_core = [&](const float* __restrict__ att, const float* __restrict__ gb,
                        float* __restrict__ xout, int strideOut, int useSkip) {
        pool[t] = -1e9f; pool[t+64] = -1e9f;
        if (t < 16) pool[t+128] = -1e9f;
        if (t < nvc) {
            int p = pairs8[t];
            int i = (p * 171) >> 11;           // p/12 for p<144
            int j = p - i*N;
            pool[p] = scoreAt(i, j, att);
        }
        if (nv > 64) {
            if (ovB) pool[p1] = scoreAt(i1, j1, att);
            if (ovC) pool[p2] = scoreAt(i2, j2, att);
        }
        // hoisted aggregate inputs (depend only on bufL/gb)
        float xj[N];
        #pragma unroll
        for (int j=0;j<N;j++) xj[j] = bufL[j*STP + t];
        float bias = gb[t];
        // row max (valid on lanes 0..11; others read row 0, harmless)
        const int rr = (t < N) ? t : 0;
        const v4f* rp = reinterpret_cast<const v4f*>(&pool[rr*N]);
        float m;
        {
            v4f q0 = rp[0], q1 = rp[1], q2 = rp[2];
            v4f qm = __builtin_elementwise_max(__builtin_elementwise_max(q0, q1), q2);
            m = fmaxf(fmaxf(qm.x, qm.y), fmaxf(qm.z, qm.w));
        }
        // wave-parallel exp over all 144 entries (rowmax via bpermute)
        {
            float rmA = bper(m, i0);
            float rmB = bper(m, i1);
            float eA = __expf(pool[p0] - rmA);
            float eB = __expf(pool[p1] - rmB);
            pool[p0] = eA;
            pool[p1] = eB;
            if (t < 16) {
                float rmC = bper(m, i2);
                pool[p2] = __expf(pool[p2] - rmC);
            }
        }
        // row sum -> inv (valid on lanes 0..11)
        float invv;
        {
            v4f w0 = rp[0], w1 = rp[1], w2 = rp[2];
            v4f ws = (w0 + w1) + w2;
            invv = 1.0f / ((ws.x + ws.y) + (ws.z + ws.w));
        }
        // aggregate own column t over all 12 rows; scale by inv_i
        {
            v4f X0 = {xj[0], xj[1], xj[2],  xj[3]};
            v4f X1 = {xj[4], xj[5], xj[6],  xj[7]};
            v4f X2 = {xj[8], xj[9], xj[10], xj[11]};
            #pragma unroll
            for (int i=0;i<N;i++) {
                const v4f* ep = reinterpret_cast<const v4f*>(&pool[i*N]);
                v4f acc = __builtin_elementwise_fma(ep[0], X0,
                          __builtin_elementwise_fma(ep[1], X1, ep[2]*X2));
                float dot = (acc.x + acc.y) + (acc.z + acc.w);
                float inv_i = __shfl(invv, i);
                float r = fmaf(dot, inv_i, bias);
                if (useSkip) r = fmaf(ALPHA, skipv[i], r);
                xout[i*strideOut + t] = fmaxf(r, 0.f);
            }
        }
    };

    // ---- MFMA stage (TW only): bufL/bufR <- xin @ {wl, wr} (bf16) ----
    auto stage_mfma = [&](const float* __restrict__ xin, int strideIn, int matL) {
        const int m = t & 15, quad = t >> 4;
        const int mc = (m < N) ? m : 0;        // clamp: rows 12..15 discarded anyway
        i4 aF[2];
        #pragma unroll
        for (int kt=0; kt<2; kt++) {
            const float* xp = &xin[mc*strideIn + kt*32 + quad*8];
            v4f lo = *reinterpret_cast<const v4f*>(xp);
            v4f hi = *reinterpret_cast<const v4f*>(xp + 4);
            unsigned u0 = __float_as_uint(lo.x) + 0x8000u, u1 = __float_as_uint(lo.y) + 0x8000u;
            unsigned u2 = __float_as_uint(lo.z) + 0x8000u, u3 = __float_as_uint(lo.w) + 0x8000u;
            unsigned u4 = __float_as_uint(hi.x) + 0x8000u, u5 = __float_as_uint(hi.y) + 0x8000u;
            unsigned u6 = __float_as_uint(hi.z) + 0x8000u, u7 = __float_as_uint(hi.w) + 0x8000u;
            i4 a;
            a.x = (int)__builtin_amdgcn_perm(u1, u0, 0x07060302u);
            a.y = (int)__builtin_amdgcn_perm(u3, u2, 0x07060302u);
            a.z = (int)__builtin_amdgcn_perm(u5, u4, 0x07060302u);
            a.w = (int)__builtin_amdgcn_perm(u7, u6, 0x07060302u);
            aF[kt] = a;
        }
        const i4* bbase = reinterpret_cast<const i4*>(wsT + 4096);
        #pragma unroll
        for (int mm=0; mm<2; mm++) {
            const i4* bp = bbase + (matL + mm)*512;
            v4f acc[4] = {z4, z4, z4, z4};
            #pragma unroll
            for (int nt=0; nt<4; nt++) {
                i4 b0 = bp[(0*4+nt)*64 + t];
                i4 b1 = bp[(1*4+nt)*64 + t];
                acc[nt] = __builtin_amdgcn_mfma_f32_16x16x32_bf16(as_v8s(aF[0]), as_v8s(b0), acc[nt], 0, 0, 0);
                acc[nt] = __builtin_amdgcn_mfma_f32_16x16x32_bf16(as_v8s(aF[1]), as_v8s(b1), acc[nt], 0, 0, 0);
            }
            float* dst = (mm == 0) ? bufL : bufR;
            if (quad < 3) {
                #pragma unroll
                for (int nt=0; nt<4; nt++) {
                    #pragma unroll
                    for (int r=0; r<4; r++)
                        dst[(quad*4+r)*STP + nt*16 + m] = acc[nt][r];
                }
            }
        }
    };

    // ---- fp32 VALU stage (fallback when TW=false) ----
    auto stage = [&](const float* __restrict__ xin, int strideIn,
                     const float* __restrict__ wl, const float* __restrict__ wr) {
        v2f al[N], ar[N];
        #pragma unroll
        for (int i=0;i<N;i++) { al[i] = z2; ar[i] = z2; }
        for (int c=0;c<HID;c+=4) {
            v2f wl01 = (v2f){wl[(c+0)*HID+t], wl[(c+1)*HID+t]};
            v2f wl23 = (v2f){wl[(c+2)*HID+t], wl[(c+3)*HID+t]};
            v2f wr01 = (v2f){wr[(c+0)*HID+t], wr[(c+1)*HID+t]};
            v2f wr23 = (v2f){wr[(c+2)*HID+t], wr[(c+3)*HID+t]};
            #pragma unroll
            for (int i=0;i<N;i++) {
                v4f xv = *reinterpret_cast<const v4f*>(&xin[i*strideIn + c]);
                al[i] = __builtin_elementwise_fma(xv.xy, wl01, al[i]);
                al[i] = __builtin_elementwise_fma(xv.zw, wl23, al[i]);
                ar[i] = __builtin_elementwise_fma(xv.xy, wr01, ar[i]);
                ar[i] = __builtin_elementwise_fma(xv.zw, wr23, ar[i]);
            }
        }
        #pragma unroll
        for (int i=0;i<N;i++) {
            bufL[i*STP + t] = al[i].x + al[i].y;
            bufR[i*STP + t] = ar[i].x + ar[i].y;
        }
    };

    // ---- GAT layer 1 (cin = 1; x0 = lat[:,2] from pool) ----
    {
        float wlv = g1_wl[t], wrv = g1_wr[t];
        #pragma unroll
        for (int i=0;i<N;i++) {
            float v = pool[i*3+2];
            bufL[i*STP + t] = v * wlv;
            bufR[i*STP + t] = v * wrv;
        }
    }
    gat_core(g1_att, g1_b, bufR, STP, 0);   // x1 -> bufR

    // ---- GAT layer 2 ----
    if (TW) stage_mfma(bufR, STP, 0); else stage(bufR, STP, g2_wl, g2_wr);
    gat_core(g2_att, g2_b, xB, HID, 0);     // x2 -> xB (persists)

    // ---- GAT layer 3 ----
    if (TW) stage_mfma(xB, HID, 2); else stage(xB, HID, g3_wl, g3_wr);
    gat_core(g3_att, g3_b, bufR, STP, 1);   // x3 -> bufR

    // ---- logits head: x3 @ lab_w + lab_b ----
    if (t < N*4) {
        int i = t >> 2, c = t & 3;
        float acc = lab_b[c];
        if (TW) {
            const float* lwT = wsT + 16384 + c*HID;
            for (int h=0;h<HID;h+=4) {
                v4f xv = *reinterpret_cast<const v4f*>(&bufR[i*STP + h]);
                v4f w4 = *reinterpret_cast<const v4f*>(&lwT[h]);
                acc = fmaf(xv.x, w4.x, acc);
                acc = fmaf(xv.y, w4.y, acc);
                acc = fmaf(xv.z, w4.z, acc);
                acc = fmaf(xv.w, w4.w, acc);
            }
        } else {
            for (int h=0;h<HID;h+=4) {
                v4f xv = *reinterpret_cast<const v4f*>(&bufR[i*STP + h]);
                acc = fmaf(xv.x, lab_w[(h+0)*4+c], acc);
                acc = fmaf(xv.y, lab_w[(h+1)*4+c], acc);
                acc = fmaf(xv.z, lab_w[(h+2)*4+c], acc);
                acc = fmaf(xv.w, lab_w[(h+3)*4+c], acc);
            }
        }
        out[OUT2 + (size_t)b*(N*4) + t] = acc;
    }

    // ---- GAT layer 4 ----
    if (TW) stage_mfma(xB, HID, 4); else stage(xB, HID, g4_wl, g4_wr);
    gat_core(g4_att, g4_b, bufR, STP, 1);   // x4 -> bufR

    // ---- values head ----
    if (t < N) {
        float acc = val_b[0];
        for (int h=0;h<HID;h+=4) {
            v4f xv = *reinterpret_cast<const v4f*>(&bufR[t*STP + h]);
            v4f w4 = *reinterpret_cast<const v4f*>(&val_w[h]);
            acc = fmaf(xv.x, w4.x, acc);
            acc = fmaf(xv.y, w4.y, acc);
            acc = fmaf(xv.z, w4.z, acc);
            acc = fmaf(xv.w, w4.w, acc);
        }
        out[OUT3 + (size_t)b*N + t] = acc;
    }
}

extern "C" void kernel_launch(void* const* d_in, const int* in_sizes, int n_in,
                              void* d_out, int out_size, void* d_ws, size_t ws_size,
                              hipStream_t stream) {
    (void)in_sizes; (void)n_in; (void)out_size;
    const bool useT = (ws_size >= (16384 + 256)*sizeof(float));
    if (useT) {
        prep_kernel<<<dim3(113), dim3(64), 0, stream>>>(
            (const float*)d_in[3],
            (const float*)d_in[11], (const float*)d_in[12],
            (const float*)d_in[15], (const float*)d_in[16],
            (const float*)d_in[19], (const float*)d_in[20],
            (const float*)d_in[23],
            (float*)d_ws);
        gae_kernel<true><<<dim3(4096), dim3(64), 0, stream>>>(
            (const float*)d_in[0],
            (const float*)d_in[1],  (const float*)d_in[2],
            (const float*)d_in[3],  (const float*)d_in[4],
            (const float*)d_in[5],  (const float*)d_in[6],
            (const float*)d_in[7],  (const float*)d_in[8],  (const float*)d_in[9],  (const float*)d_in[10],
            (const float*)d_in[11], (const float*)d_in[12], (const float*)d_in[13], (const float*)d_in[14],
            (const float*)d_in[15], (const float*)d_in[16], (const float*)d_in[17], (const float*)d_in[18],
            (const float*)d_in[19], (const float*)d_in[20], (const float*)d_in[21], (const float*)d_in[22],
            (const float*)d_in[23], (const float*)d_in[24],
            (const float*)d_in[25], (const float*)d_in[26],
            (const float*)d_in[27], (const float*)d_in[28],
            (const float*)d_ws,
            (float*)d_out);
    } else {
        gae_kernel<false><<<dim3(4096), dim3(64), 0, stream>>>(
            (const float*)d_in[0],
            (const float*)d_in[1],  (const float*)d_in[2],
            (const float*)d_in[3],  (const float*)d_in[4],
            (const float*)d_in[5],  (const float*)d_in[6],
            (const float*)d_in[7],  (const float*)d_in[8],  (const float*)d_in[9],  (const float*)d_in[10],
            (const float*)d_in[11], (const float*)d_in[12], (const float*)d_in[13], (const float*)d_in[14],
            (const float*)d_in[15], (const float*)d_in[16], (const float*)d_in[17], (const float*)d_in[18],
            (const float*)d_in[19], (const float*)d_in[20], (const float*)d_in[21], (const float*)d_in[22],
            (const float*)d_in[23], (const float*)d_in[24],
            (const float*)d_in[25], (const float*)d_in[26],
            (const float*)d_in[27], (const float*)d_in[28],
            nullptr,
            (float*)d_out);
    }
}